// Round 13
// baseline (1017.428 us; speedup 1.0000x reference)
//
#include <hip/hip_runtime.h>
#include <stdint.h>
#include <math.h>

#define NB 32
#define NPTS 16384
#define SS 256
#define POPP 50
#define MUU 25
#define NITERS 30

#define ROTF  ((float)0.7853981633974483)
#define SIG0R ((float)(0.7853981633974483*0.3))
#define SIG0T ((float)0.3)
#define SLOR  ((float)(0.7853981633974483*0.01))
#define SHIR  ((float)(0.7853981633974483*0.5))
#define SLOT  ((float)0.01)
#define SHIT  ((float)0.5)
#define SQRT2F ((float)1.4142135623730951)
#define ULOW  (-0.99999994f)

// ---------------- threefry2x32 (JAX-exact) ----------------
__host__ __device__ inline uint32_t rotl32(uint32_t v, int n){ return (v<<n)|(v>>(32-n)); }

__host__ __device__ inline void tf2x32(uint32_t k0, uint32_t k1, uint32_t x0, uint32_t x1,
                                       uint32_t &o0, uint32_t &o1){
  uint32_t ks2 = k0 ^ k1 ^ 0x1BD11BDAu;
  x0 += k0; x1 += k1;
#define TFR(r) { x0 += x1; x1 = rotl32(x1, r); x1 ^= x0; }
  TFR(13) TFR(15) TFR(26) TFR(6)
  x0 += k1; x1 += ks2 + 1u;
  TFR(17) TFR(29) TFR(16) TFR(24)
  x0 += ks2; x1 += k0 + 2u;
  TFR(13) TFR(15) TFR(26) TFR(6)
  x0 += k0; x1 += k1 + 3u;
  TFR(17) TFR(29) TFR(16) TFR(24)
  x0 += k1; x1 += ks2 + 4u;
  TFR(13) TFR(15) TFR(26) TFR(6)
  x0 += ks2; x1 += k0 + 5u;
#undef TFR
  o0 = x0; o1 = x1;
}

// XLA ErfInv32 (Giles), exact coefficients
__device__ inline float erfinv32(float x){
  float w = -log1pf(-x*x);
  float p;
  if (w < 5.0f) {
    w = w - 2.5f;
    p = 2.81022636e-08f;
    p = fmaf(p, w, 3.43273939e-07f);
    p = fmaf(p, w, -3.5233877e-06f);
    p = fmaf(p, w, -4.39150654e-06f);
    p = fmaf(p, w, 0.00021858087f);
    p = fmaf(p, w, -0.00125372503f);
    p = fmaf(p, w, -0.00417768164f);
    p = fmaf(p, w, 0.246640727f);
    p = fmaf(p, w, 1.50140941f);
  } else {
    w = sqrtf(w) - 3.0f;
    p = -0.000200214257f;
    p = fmaf(p, w, 0.000100950558f);
    p = fmaf(p, w, 0.00134934322f);
    p = fmaf(p, w, -0.00367342844f);
    p = fmaf(p, w, 0.00573950773f);
    p = fmaf(p, w, -0.0076224613f);
    p = fmaf(p, w, 0.00943887047f);
    p = fmaf(p, w, 1.00167406f);
    p = fmaf(p, w, 2.83297682f);
  }
  return p * x;
}

__device__ inline void axisangle_R(float ax, float ay, float az, float R[9]){
  float th = sqrtf(ax*ax + ay*ay + az*az);
  float den = th + 1e-8f;
  float ux = ax/den, uy = ay/den, uz = az/den;
  float s = sinf(th), c = cosf(th);
  float omc = 1.0f - c;
  float xx=ux*ux, yy=uy*uy, zz=uz*uz;
  float xy=ux*uy, xz=ux*uz, yz=uy*uz;
  R[0] = 1.0f + omc*(-(yy+zz));
  R[1] = s*(-uz) + omc*xy;
  R[2] = s*uy    + omc*xz;
  R[3] = s*uz    + omc*xy;
  R[4] = 1.0f + omc*(-(xx+zz));
  R[5] = s*(-ux) + omc*yz;
  R[6] = s*(-uy) + omc*xz;
  R[7] = s*ux    + omc*yz;
  R[8] = 1.0f + omc*(-(xx+yy));
}

struct WArr { float w[MUU]; };

// ---------------- init ----------------
__global__ void k_init(float* mean, float* sigma, float* gbest_pos, float* gbest_fit){
  int i = blockIdx.x*blockDim.x + threadIdx.x;
  if (i < NB*6){
    mean[i] = 0.0f;
    gbest_pos[i] = 0.0f;
    int d = i % 6;
    sigma[i] = (d < 3) ? SIG0R : SIG0T;
  }
  if (i < NB) gbest_fit[i] = INFINITY;
}

// ---------------- permutation sort-keys gen ----------------
// comp = key<<28 | pos<<14 | val  (key=32b, pos/val 14b for N=16384)
__global__ void k_genperm(uint64_t* comp, uint32_t sa0, uint32_t sa1,
                          uint32_t sb0, uint32_t sb1, int round){
  int i = blockIdx.x*blockDim.x + threadIdx.x;
  if (i >= 2*NPTS) return;
  int a = i >> 14;
  int idx = i & (NPTS-1);
  uint32_t kk0 = a ? sb0 : sa0;
  uint32_t kk1 = a ? sb1 : sa1;
  uint32_t o0,o1; tf2x32(kk0, kk1, 0u, (uint32_t)idx, o0, o1);
  uint32_t key = o0 ^ o1;   // partitionable 32-bit random bits
  uint64_t val = (round == 0) ? (uint64_t)idx : (comp[i] & 0x3FFFull);
  comp[i] = ((uint64_t)key << 28) | ((uint64_t)idx << 14) | val;
}

// ---------------- bitonic sort (ascending by u64) ----------------
__global__ __launch_bounds__(1024) void k_sort_local(uint64_t* comp){
  __shared__ uint64_t buf[4096];
  int c = blockIdx.x;            // 8 chunks across 2 arrays
  int base = c * 4096;
  int abase = (c & 3) * 4096;    // index within its own 16384 array
  for (int t = threadIdx.x; t < 4096; t += 1024) buf[t] = comp[base + t];
  __syncthreads();
  for (int k = 2; k <= 4096; k <<= 1){
    for (int j = k >> 1; j > 0; j >>= 1){
      for (int idx = threadIdx.x; idx < 2048; idx += 1024){
        int i = ((idx & ~(j-1)) << 1) | (idx & (j-1));
        int pi = i | j;
        bool dir = (((abase + i) & k) == 0);
        uint64_t A = buf[i], Bv = buf[pi];
        bool sw = dir ? (A > Bv) : (A < Bv);
        if (sw){ buf[i] = Bv; buf[pi] = A; }
      }
      __syncthreads();
    }
  }
  for (int t = threadIdx.x; t < 4096; t += 1024) comp[base + t] = buf[t];
}

__global__ void k_sort_global(uint64_t* comp, int k, int j){
  int t = blockIdx.x*blockDim.x + threadIdx.x;
  if (t >= NPTS) return;            // 8192 pairs per array * 2 arrays
  int a = t >> 13;
  int idx = t & 8191;
  int i = ((idx & ~(j-1)) << 1) | (idx & (j-1));
  int pi = i | j;
  bool dir = ((i & k) == 0);
  uint64_t* arr = comp + (size_t)a * NPTS;
  uint64_t A = arr[i], Bv = arr[pi];
  bool sw = dir ? (A > Bv) : (A < Bv);
  if (sw){ arr[i] = Bv; arr[pi] = A; }
}

__global__ __launch_bounds__(1024) void k_sort_finish(uint64_t* comp, int k){
  __shared__ uint64_t buf[4096];
  int c = blockIdx.x;
  int base = c * 4096;
  int abase = (c & 3) * 4096;
  for (int t = threadIdx.x; t < 4096; t += 1024) buf[t] = comp[base + t];
  __syncthreads();
  for (int j = 2048; j > 0; j >>= 1){
    for (int idx = threadIdx.x; idx < 2048; idx += 1024){
      int i = ((idx & ~(j-1)) << 1) | (idx & (j-1));
      int pi = i | j;
      bool dir = (((abase + i) & k) == 0);
      uint64_t A = buf[i], Bv = buf[pi];
      bool sw = dir ? (A > Bv) : (A < Bv);
      if (sw){ buf[i] = Bv; buf[pi] = A; }
    }
    __syncthreads();
  }
  for (int t = threadIdx.x; t < 4096; t += 1024) comp[base + t] = buf[t];
}

__global__ void k_gather(const uint64_t* comp, const float* source, const float* target,
                         float* src_sub, float* tgt_sub){
  int t = blockIdx.x*blockDim.x + threadIdx.x;
  if (t >= 2*NB*SS) return;
  int a = t / (NB*SS);
  int r = t % (NB*SS);
  int b = r / SS;
  int s2 = r % SS;
  int val = (int)(comp[(size_t)a*NPTS + s2] & 0x3FFFull);
  const float* inp = a ? target : source;
  float* outp = a ? tgt_sub : src_sub;
  for (int d = 0; d < 3; ++d)
    outp[((size_t)b*SS + s2)*3 + d] = inp[((size_t)b*NPTS + val)*3 + d];
}

// ---------------- sample + eval: split-range fused passes ----------------
// 1 candidate per block, 128 threads = 2 waves. Each lane owns 4 x's AND 4 y's
// (registers); each wave iterates its HALF of t in ONE fused loop updating 8
// independent min chains from 2 broadcast reads. Wave partials combine in LDS.
// vs r9: LDS broadcasts halved (1024->512), ILP 2->8, ALU unchanged.
__global__ __launch_bounds__(128) void k_se(uint32_t ka, uint32_t kb,
    const float* __restrict__ mean, const float* __restrict__ sigma,
    const float* __restrict__ src_sub, const float* __restrict__ tgt_sub,
    float* __restrict__ z_buf, float* __restrict__ off_buf,
    float* __restrict__ fit){
  int c = blockIdx.x;
  int b = c / POPP;
  int tid = threadIdx.x;
  int wave = tid >> 6;
  int lane = tid & 63;
  __shared__ float qoff[6];
  __shared__ float4 ysd[SS];     // (-2Y, |Y|^2)
  __shared__ float4 xsd[SS];     // (-2PX, |PX|^2) transformed
  __shared__ float rmp[2][SS];   // per-wave rmin partials
  __shared__ float cmp[2][SS];   // per-wave cmin partials
  __shared__ float wpart[2];

  // ---- inline sampling (bitwise-identical trajectory) ----
  if (tid < 6){
    int i = c*6 + tid;
    uint32_t o0,o1; tf2x32(ka, kb, 0u, (uint32_t)i, o0, o1);
    uint32_t bits = o0 ^ o1;
    float u = __uint_as_float((bits >> 9) | 0x3F800000u) - 1.0f;
    u = u * 2.0f + ULOW;
    u = fmaxf(ULOW, u);
    float zz = SQRT2F * erfinv32(u);
    float m = mean[b*6 + tid], sg = sigma[b*6 + tid];
    float v = fmaf(sg, zz, m);
    float lim = (tid < 3) ? ROTF : 1.0f;
    v = fminf(fmaxf(v, -lim), lim);
    z_buf[i] = zz; off_buf[i] = v; qoff[tid] = v;
  }
  __syncthreads();

  float R[9];
  axisangle_R(qoff[0], qoff[1], qoff[2], R);
  float tx=qoff[3], ty=qoff[4], tz=qoff[5];

  // ---- stage Y: (-2Y, sy), 2 per thread ----
  for (int i = tid; i < SS; i += 128){
    const float* tp = tgt_sub + ((size_t)b*SS + i)*3;
    float Y0=tp[0], Y1=tp[1], Y2=tp[2];
    float sy = fmaf(Y2,Y2, fmaf(Y1,Y1, Y0*Y0));
    ysd[i] = make_float4(-2.0f*Y0, -2.0f*Y1, -2.0f*Y2, sy);
  }

  // ---- transform + stage X: 2 per thread ----
  #pragma unroll
  for (int rep = 0; rep < 2; ++rep){
    int xi = tid + rep*128;
    const float* sp = src_sub + ((size_t)b*SS + xi)*3;
    float X0=sp[0], X1=sp[1], X2=sp[2];
    float px = fmaf(X2, R[2], fmaf(X1, R[1], X0*R[0])) + tx;
    float py = fmaf(X2, R[5], fmaf(X1, R[4], X0*R[3])) + ty;
    float pz = fmaf(X2, R[8], fmaf(X1, R[7], X0*R[6])) + tz;
    float sx = fmaf(pz,pz, fmaf(py,py, px*px));
    xsd[xi] = make_float4(-2.0f*px, -2.0f*py, -2.0f*pz, sx);
  }
  __syncthreads();

  // ---- load own 4 x's and 4 y's into registers (exact: -0.5*(-2v) == v) ----
  float pxj[4],pyj[4],pzj[4],sxj[4];
  float yxj[4],yyj[4],yzj[4],syj[4];
  #pragma unroll
  for (int j = 0; j < 4; ++j){
    int i = lane + 64*j;
    float4 xv = xsd[i];
    pxj[j] = -0.5f*xv.x; pyj[j] = -0.5f*xv.y; pzj[j] = -0.5f*xv.z; sxj[j] = xv.w;
    float4 yv = ysd[i];
    yxj[j] = -0.5f*yv.x; yyj[j] = -0.5f*yv.y; yzj[j] = -0.5f*yv.z; syj[j] = yv.w;
  }

  // ---- fused split-range pass: wave w covers t in [w*128, w*128+128) ----
  float rm0=INFINITY, rm1=INFINITY, rm2=INFINITY, rm3=INFINITY;
  float cm0=INFINITY, cm1=INFINITY, cm2=INFINITY, cm3=INFINITY;
  int tbeg = wave*128;
  #pragma unroll 8
  for (int t = tbeg; t < tbeg+128; ++t){
    float4 yv = ysd[t];
    float4 xv = xsd[t];
    rm0 = fminf(rm0, fmaf(pxj[0], yv.x, fmaf(pyj[0], yv.y, fmaf(pzj[0], yv.z, yv.w))));
    rm1 = fminf(rm1, fmaf(pxj[1], yv.x, fmaf(pyj[1], yv.y, fmaf(pzj[1], yv.z, yv.w))));
    rm2 = fminf(rm2, fmaf(pxj[2], yv.x, fmaf(pyj[2], yv.y, fmaf(pzj[2], yv.z, yv.w))));
    rm3 = fminf(rm3, fmaf(pxj[3], yv.x, fmaf(pyj[3], yv.y, fmaf(pzj[3], yv.z, yv.w))));
    cm0 = fminf(cm0, fmaf(yxj[0], xv.x, fmaf(yyj[0], xv.y, fmaf(yzj[0], xv.z, xv.w))));
    cm1 = fminf(cm1, fmaf(yxj[1], xv.x, fmaf(yyj[1], xv.y, fmaf(yzj[1], xv.z, xv.w))));
    cm2 = fminf(cm2, fmaf(yxj[2], xv.x, fmaf(yyj[2], xv.y, fmaf(yzj[2], xv.z, xv.w))));
    cm3 = fminf(cm3, fmaf(yxj[3], xv.x, fmaf(yyj[3], xv.y, fmaf(yzj[3], xv.z, xv.w))));
  }

  // ---- write wave partials ----
  rmp[wave][lane+  0] = rm0;  cmp[wave][lane+  0] = cm0;
  rmp[wave][lane+ 64] = rm1;  cmp[wave][lane+ 64] = cm1;
  rmp[wave][lane+128] = rm2;  cmp[wave][lane+128] = cm2;
  rmp[wave][lane+192] = rm3;  cmp[wave][lane+192] = cm3;
  __syncthreads();

  // ---- combine: wave 0 finalizes x-side, wave 1 finalizes y-side ----
  float acc;
  if (wave == 0){
    float f0 = sxj[0] + fminf(rmp[0][lane+  0], rmp[1][lane+  0]);
    float f1 = sxj[1] + fminf(rmp[0][lane+ 64], rmp[1][lane+ 64]);
    float f2 = sxj[2] + fminf(rmp[0][lane+128], rmp[1][lane+128]);
    float f3 = sxj[3] + fminf(rmp[0][lane+192], rmp[1][lane+192]);
    acc = (f0 + f1) + (f2 + f3);
  } else {
    float f0 = syj[0] + fminf(cmp[0][lane+  0], cmp[1][lane+  0]);
    float f1 = syj[1] + fminf(cmp[0][lane+ 64], cmp[1][lane+ 64]);
    float f2 = syj[2] + fminf(cmp[0][lane+128], cmp[1][lane+128]);
    float f3 = syj[3] + fminf(cmp[0][lane+192], cmp[1][lane+192]);
    acc = (f0 + f1) + (f2 + f3);
  }

  for (int m = 32; m > 0; m >>= 1) acc += __shfl_xor(acc, m, 64);
  if (lane == 0) wpart[wave] = acc;
  __syncthreads();
  if (tid == 0) fit[c] = (wpart[0] + wpart[1]) * (1.0f/256.0f);
}

// ---------------- chamfer fitness for the final mean (r9 version, 1 dispatch) ----------------
__global__ __launch_bounds__(128) void k_eval(const float* __restrict__ pos, int Pn,
    const float* __restrict__ src_sub, const float* __restrict__ tgt_sub,
    float* __restrict__ fit){
  int c = blockIdx.x;
  int b = c / Pn;
  int tid = threadIdx.x;
  int wave = tid >> 6;
  int lane = tid & 63;
  __shared__ float4 ysd[SS];
  __shared__ float4 xsd[SS];
  __shared__ float wpart[2];

  const float* q = pos + (size_t)c*6;
  float R[9];
  axisangle_R(q[0], q[1], q[2], R);
  float tx=q[3], ty=q[4], tz=q[5];

  for (int i = tid; i < SS; i += 128){
    const float* tp = tgt_sub + ((size_t)b*SS + i)*3;
    float Y0=tp[0], Y1=tp[1], Y2=tp[2];
    float sy = fmaf(Y2,Y2, fmaf(Y1,Y1, Y0*Y0));
    ysd[i] = make_float4(-2.0f*Y0, -2.0f*Y1, -2.0f*Y2, sy);
  }

  int xi0 = wave*128 + lane;
  int xi1 = xi0 + 64;
  float px0,py0,pz0,sx0, px1,py1,pz1,sx1;
  {
    const float* sp = src_sub + ((size_t)b*SS + xi0)*3;
    float X0=sp[0], X1=sp[1], X2=sp[2];
    px0 = fmaf(X2, R[2], fmaf(X1, R[1], X0*R[0])) + tx;
    py0 = fmaf(X2, R[5], fmaf(X1, R[4], X0*R[3])) + ty;
    pz0 = fmaf(X2, R[8], fmaf(X1, R[7], X0*R[6])) + tz;
    sx0 = fmaf(pz0,pz0, fmaf(py0,py0, px0*px0));
    xsd[xi0] = make_float4(-2.0f*px0, -2.0f*py0, -2.0f*pz0, sx0);
  }
  {
    const float* sp = src_sub + ((size_t)b*SS + xi1)*3;
    float X0=sp[0], X1=sp[1], X2=sp[2];
    px1 = fmaf(X2, R[2], fmaf(X1, R[1], X0*R[0])) + tx;
    py1 = fmaf(X2, R[5], fmaf(X1, R[4], X0*R[3])) + ty;
    pz1 = fmaf(X2, R[8], fmaf(X1, R[7], X0*R[6])) + tz;
    sx1 = fmaf(pz1,pz1, fmaf(py1,py1, px1*px1));
    xsd[xi1] = make_float4(-2.0f*px1, -2.0f*py1, -2.0f*pz1, sx1);
  }
  __syncthreads();

  float rm0 = INFINITY, rm1 = INFINITY;
  #pragma unroll 8
  for (int t = 0; t < SS; ++t){
    float4 yv = ysd[t];
    rm0 = fminf(rm0, fmaf(px0, yv.x, fmaf(py0, yv.y, fmaf(pz0, yv.z, yv.w))));
    rm1 = fminf(rm1, fmaf(px1, yv.x, fmaf(py1, yv.y, fmaf(pz1, yv.z, yv.w))));
  }
  float acc = (sx0 + rm0) + (sx1 + rm1);

  float4 yv0 = ysd[xi0];
  float4 yv1 = ysd[xi1];
  float yx0 = -0.5f*yv0.x, yy0 = -0.5f*yv0.y, yz0 = -0.5f*yv0.z, sy0 = yv0.w;
  float yx1 = -0.5f*yv1.x, yy1 = -0.5f*yv1.y, yz1 = -0.5f*yv1.z, sy1 = yv1.w;
  float cm0 = INFINITY, cm1 = INFINITY;
  #pragma unroll 8
  for (int t = 0; t < SS; ++t){
    float4 xv = xsd[t];
    cm0 = fminf(cm0, fmaf(yx0, xv.x, fmaf(yy0, xv.y, fmaf(yz0, xv.z, xv.w))));
    cm1 = fminf(cm1, fmaf(yx1, xv.x, fmaf(yy1, xv.y, fmaf(yz1, xv.z, xv.w))));
  }
  acc += (sy0 + cm0) + (sy1 + cm1);

  for (int m = 32; m > 0; m >>= 1) acc += __shfl_xor(acc, m, 64);
  if (lane == 0) wpart[wave] = acc;
  __syncthreads();
  if (tid == 0) fit[c] = (wpart[0] + wpart[1]) * (1.0f/256.0f);
}

// ---------------- selection + update (round-5 verbatim) ----------------
__global__ __launch_bounds__(64) void k_update(const float* __restrict__ fit,
    const float* __restrict__ off, const float* __restrict__ z,
    float* mean, float* sigma, float* gbest_pos, float* gbest_fit, WArr W){
  int b = blockIdx.x;
  int tid = threadIdx.x;
  __shared__ float lfit[POPP];
  __shared__ int order[POPP];
  __shared__ float mn[6], mz[6];
  if (tid < POPP) lfit[tid] = fit[b*POPP + tid];
  __syncthreads();
  if (tid < POPP){
    float f = lfit[tid];
    int r = 0;
    for (int j = 0; j < POPP; ++j){
      float fj = lfit[j];
      r += (fj < f) || (fj == f && j < tid);   // stable ascending rank
    }
    order[r] = tid;
  }
  __syncthreads();
  if (tid < 6){
    float a = 0.0f, bz = 0.0f;
    for (int m = 0; m < MUU; ++m){
      int idx = order[m];
      a  = fmaf(W.w[m], off[((size_t)b*POPP + idx)*6 + tid], a);
      bz = fmaf(W.w[m], z  [((size_t)b*POPP + idx)*6 + tid], bz);
    }
    mn[tid] = a; mz[tid] = bz;
  }
  __syncthreads();
  if (tid == 0){
    float avg = (((((fabsf(mz[0])+fabsf(mz[1]))+fabsf(mz[2]))+fabsf(mz[3]))+fabsf(mz[4]))+fabsf(mz[5])) / 6.0f;
    float e = expf(0.3f * (avg - 1.0f));
    for (int d = 0; d < 6; ++d){
      float sN = sigma[b*6 + d] * e;
      float lo = (d < 3) ? SLOR : SLOT;
      float hi = (d < 3) ? SHIR : SHIT;
      sN = fminf(fmaxf(sN, lo), hi);
      sigma[b*6 + d] = sN;
      mean[b*6 + d] = mn[d];
    }
    int i0 = order[0];
    float bf = lfit[i0];
    if (bf < gbest_fit[b]){
      gbest_fit[b] = bf;
      for (int d = 0; d < 6; ++d) gbest_pos[b*6 + d] = off[((size_t)b*POPP + i0)*6 + d];
    }
  }
}

// ---------------- finalize: choose gbest vs mean, emit R,t ----------------
__global__ void k_finalize(const float* mean, const float* mean_fit,
                           const float* gbest_pos, const float* gbest_fit, float* out){
  int b = blockIdx.x;
  if (threadIdx.x != 0) return;
  bool um = mean_fit[b] < gbest_fit[b];
  float g[6];
  for (int d = 0; d < 6; ++d) g[d] = um ? mean[b*6 + d] : gbest_pos[b*6 + d];
  float R[9];
  axisangle_R(g[0], g[1], g[2], R);
  for (int i = 0; i < 9; ++i) out[b*9 + i] = R[i];
  for (int d = 0; d < 3; ++d) out[NB*9 + b*3 + d] = g[3 + d];
}

__global__ void k_aligned(const float* __restrict__ src, const float* __restrict__ out_rt,
                          float* __restrict__ aligned){
  int idx = blockIdx.x*blockDim.x + threadIdx.x;
  if (idx >= NB*NPTS) return;
  int b = idx / NPTS;
  const float* R = out_rt + b*9;
  const float* t = out_rt + NB*9 + b*3;
  const float* p = src + (size_t)idx*3;
  float X0=p[0], X1=p[1], X2=p[2];
  float* o = aligned + (size_t)idx*3;
  o[0] = fmaf(X2, R[2], fmaf(X1, R[1], X0*R[0])) + t[0];
  o[1] = fmaf(X2, R[5], fmaf(X1, R[4], X0*R[3])) + t[1];
  o[2] = fmaf(X2, R[8], fmaf(X1, R[7], X0*R[6])) + t[2];
}

// ---------------- host ----------------
struct HKey { uint32_t a, b; };
static inline HKey h_tf(HKey k, uint32_t x0, uint32_t x1){
  uint32_t o0,o1; tf2x32(k.a, k.b, x0, x1, o0, o1);
  return {o0, o1};
}

static void run_sort(uint64_t* comp, hipStream_t stream){
  hipLaunchKernelGGL(k_sort_local,  dim3(8),  dim3(1024), 0, stream, comp);
  hipLaunchKernelGGL(k_sort_global, dim3(64), dim3(256),  0, stream, comp, 8192, 4096);
  hipLaunchKernelGGL(k_sort_finish, dim3(8),  dim3(1024), 0, stream, comp, 8192);
  hipLaunchKernelGGL(k_sort_global, dim3(64), dim3(256),  0, stream, comp, 16384, 8192);
  hipLaunchKernelGGL(k_sort_global, dim3(64), dim3(256),  0, stream, comp, 16384, 4096);
  hipLaunchKernelGGL(k_sort_finish, dim3(8),  dim3(1024), 0, stream, comp, 16384);
}

extern "C" void kernel_launch(void* const* d_in, const int* in_sizes, int n_in,
                              void* d_out, int out_size, void* d_ws, size_t ws_size,
                              hipStream_t stream){
  const float* source = (const float*)d_in[0];
  const float* target = (const float*)d_in[1];
  float* out = (float*)d_out;

  // ---- workspace layout (256B aligned chunks) ----
  uint8_t* w = (uint8_t*)d_ws;
  size_t o = 0;
  auto alloc = [&](size_t bytes){ void* p = w + o; o += (bytes + 255) & ~(size_t)255; return p; };
  uint64_t* comp   = (uint64_t*)alloc(2*(size_t)NPTS*8);
  float* src_sub   = (float*)alloc((size_t)NB*SS*3*4);
  float* tgt_sub   = (float*)alloc((size_t)NB*SS*3*4);
  float* z_buf     = (float*)alloc((size_t)NB*POPP*6*4);
  float* off_buf   = (float*)alloc((size_t)NB*POPP*6*4);
  float* fit_buf   = (float*)alloc((size_t)NB*POPP*4);
  float* mean_buf  = (float*)alloc((size_t)NB*6*4);
  float* sigma_buf = (float*)alloc((size_t)NB*6*4);
  float* gb_pos    = (float*)alloc((size_t)NB*6*4);
  float* gb_fit    = (float*)alloc((size_t)NB*4);
  float* mean_fit  = (float*)alloc((size_t)NB*4);
  (void)ws_size; (void)in_sizes; (void)n_in; (void)out_size;

  // ---- host-side JAX key derivation (threefry, partitionable mode) ----
  HKey key0 = {0u, 42u};
  HKey k1 = h_tf(key0, 0u, 0u);
  HKey k2 = h_tf(key0, 0u, 1u);
  HKey k3 = h_tf(key0, 0u, 2u);
  HKey srcA  = h_tf(k1, 0u, 0u);
  HKey srcS1 = h_tf(k1, 0u, 1u);
  HKey srcS2 = h_tf(srcA, 0u, 1u);
  HKey tgtA  = h_tf(k2, 0u, 0u);
  HKey tgtS1 = h_tf(k2, 0u, 1u);
  HKey tgtS2 = h_tf(tgtA, 0u, 1u);
  HKey itk[NITERS];
  for (int j = 0; j < NITERS; ++j) itk[j] = h_tf(k3, 0u, (uint32_t)j);

  // ---- recombination weights (numpy double math, cast f32) ----
  WArr W;
  {
    double lw[MUU], s = 0.0;
    for (int m = 0; m < MUU; ++m){ lw[m] = log((double)MUU + 0.5) - log((double)(m+1)); s += lw[m]; }
    for (int m = 0; m < MUU; ++m) W.w[m] = (float)(lw[m] / s);
  }

  hipLaunchKernelGGL(k_init, dim3(1), dim3(256), 0, stream, mean_buf, sigma_buf, gb_pos, gb_fit);

  // ---- permutations (2 stable-sort rounds each, both arrays together) ----
  hipLaunchKernelGGL(k_genperm, dim3(128), dim3(256), 0, stream,
                     comp, srcS1.a, srcS1.b, tgtS1.a, tgtS1.b, 0);
  run_sort(comp, stream);
  hipLaunchKernelGGL(k_genperm, dim3(128), dim3(256), 0, stream,
                     comp, srcS2.a, srcS2.b, tgtS2.a, tgtS2.b, 1);
  run_sort(comp, stream);
  hipLaunchKernelGGL(k_gather, dim3(64), dim3(256), 0, stream,
                     comp, source, target, src_sub, tgt_sub);

  // ---- CMA-ES main loop: sample+eval fused, update separate ----
  for (int it = 0; it < NITERS; ++it){
    hipLaunchKernelGGL(k_se, dim3(NB*POPP), dim3(128), 0, stream,
                       itk[it].a, itk[it].b, mean_buf, sigma_buf,
                       src_sub, tgt_sub, z_buf, off_buf, fit_buf);
    hipLaunchKernelGGL(k_update, dim3(NB), dim3(64), 0, stream,
                       fit_buf, off_buf, z_buf, mean_buf, sigma_buf, gb_pos, gb_fit, W);
  }

  // ---- final mean evaluation + output ----
  hipLaunchKernelGGL(k_eval, dim3(NB), dim3(128), 0, stream,
                     mean_buf, 1, src_sub, tgt_sub, mean_fit);
  hipLaunchKernelGGL(k_finalize, dim3(NB), dim3(64), 0, stream,
                     mean_buf, mean_fit, gb_pos, gb_fit, out);
  hipLaunchKernelGGL(k_aligned, dim3((NB*NPTS + 255)/256), dim3(256), 0, stream,
                     source, out, out + NB*9 + NB*3);
}

// Round 14
// 950.011 us; speedup vs baseline: 1.0710x; 1.0710x over previous
//
#include <hip/hip_runtime.h>
#include <stdint.h>
#include <math.h>

#define NB 32
#define NPTS 16384
#define SS 256
#define POPP 50
#define MUU 25
#define NITERS 30

#define ROTF  ((float)0.7853981633974483)
#define SIG0R ((float)(0.7853981633974483*0.3))
#define SIG0T ((float)0.3)
#define SLOR  ((float)(0.7853981633974483*0.01))
#define SHIR  ((float)(0.7853981633974483*0.5))
#define SLOT  ((float)0.01)
#define SHIT  ((float)0.5)
#define SQRT2F ((float)1.4142135623730951)
#define ULOW  (-0.99999994f)

// ---------------- threefry2x32 (JAX-exact) ----------------
__host__ __device__ inline uint32_t rotl32(uint32_t v, int n){ return (v<<n)|(v>>(32-n)); }

__host__ __device__ inline void tf2x32(uint32_t k0, uint32_t k1, uint32_t x0, uint32_t x1,
                                       uint32_t &o0, uint32_t &o1){
  uint32_t ks2 = k0 ^ k1 ^ 0x1BD11BDAu;
  x0 += k0; x1 += k1;
#define TFR(r) { x0 += x1; x1 = rotl32(x1, r); x1 ^= x0; }
  TFR(13) TFR(15) TFR(26) TFR(6)
  x0 += k1; x1 += ks2 + 1u;
  TFR(17) TFR(29) TFR(16) TFR(24)
  x0 += ks2; x1 += k0 + 2u;
  TFR(13) TFR(15) TFR(26) TFR(6)
  x0 += k0; x1 += k1 + 3u;
  TFR(17) TFR(29) TFR(16) TFR(24)
  x0 += k1; x1 += ks2 + 4u;
  TFR(13) TFR(15) TFR(26) TFR(6)
  x0 += ks2; x1 += k0 + 5u;
#undef TFR
  o0 = x0; o1 = x1;
}

// XLA ErfInv32 (Giles), exact coefficients
__device__ inline float erfinv32(float x){
  float w = -log1pf(-x*x);
  float p;
  if (w < 5.0f) {
    w = w - 2.5f;
    p = 2.81022636e-08f;
    p = fmaf(p, w, 3.43273939e-07f);
    p = fmaf(p, w, -3.5233877e-06f);
    p = fmaf(p, w, -4.39150654e-06f);
    p = fmaf(p, w, 0.00021858087f);
    p = fmaf(p, w, -0.00125372503f);
    p = fmaf(p, w, -0.00417768164f);
    p = fmaf(p, w, 0.246640727f);
    p = fmaf(p, w, 1.50140941f);
  } else {
    w = sqrtf(w) - 3.0f;
    p = -0.000200214257f;
    p = fmaf(p, w, 0.000100950558f);
    p = fmaf(p, w, 0.00134934322f);
    p = fmaf(p, w, -0.00367342844f);
    p = fmaf(p, w, 0.00573950773f);
    p = fmaf(p, w, -0.0076224613f);
    p = fmaf(p, w, 0.00943887047f);
    p = fmaf(p, w, 1.00167406f);
    p = fmaf(p, w, 2.83297682f);
  }
  return p * x;
}

__device__ inline void axisangle_R(float ax, float ay, float az, float R[9]){
  float th = sqrtf(ax*ax + ay*ay + az*az);
  float den = th + 1e-8f;
  float ux = ax/den, uy = ay/den, uz = az/den;
  float s = sinf(th), c = cosf(th);
  float omc = 1.0f - c;
  float xx=ux*ux, yy=uy*uy, zz=uz*uz;
  float xy=ux*uy, xz=ux*uz, yz=uy*uz;
  R[0] = 1.0f + omc*(-(yy+zz));
  R[1] = s*(-uz) + omc*xy;
  R[2] = s*uy    + omc*xz;
  R[3] = s*uz    + omc*xy;
  R[4] = 1.0f + omc*(-(xx+zz));
  R[5] = s*(-ux) + omc*yz;
  R[6] = s*(-uy) + omc*xz;
  R[7] = s*ux    + omc*yz;
  R[8] = 1.0f + omc*(-(xx+yy));
}

struct WArr { float w[MUU]; };

// ---------------- init ----------------
__global__ void k_init(float* mean, float* sigma, float* gbest_pos, float* gbest_fit){
  int i = blockIdx.x*blockDim.x + threadIdx.x;
  if (i < NB*6){
    mean[i] = 0.0f;
    gbest_pos[i] = 0.0f;
    int d = i % 6;
    sigma[i] = (d < 3) ? SIG0R : SIG0T;
  }
  if (i < NB) gbest_fit[i] = INFINITY;
}

// ---------------- permutation sort-keys gen ----------------
// comp = key<<28 | pos<<14 | val  (key=32b, pos/val 14b for N=16384)
__global__ void k_genperm(uint64_t* comp, uint32_t sa0, uint32_t sa1,
                          uint32_t sb0, uint32_t sb1, int round){
  int i = blockIdx.x*blockDim.x + threadIdx.x;
  if (i >= 2*NPTS) return;
  int a = i >> 14;
  int idx = i & (NPTS-1);
  uint32_t kk0 = a ? sb0 : sa0;
  uint32_t kk1 = a ? sb1 : sa1;
  uint32_t o0,o1; tf2x32(kk0, kk1, 0u, (uint32_t)idx, o0, o1);
  uint32_t key = o0 ^ o1;   // partitionable 32-bit random bits
  uint64_t val = (round == 0) ? (uint64_t)idx : (comp[i] & 0x3FFFull);
  comp[i] = ((uint64_t)key << 28) | ((uint64_t)idx << 14) | val;
}

// ---------------- bitonic sort (ascending by u64) ----------------
__global__ __launch_bounds__(1024) void k_sort_local(uint64_t* comp){
  __shared__ uint64_t buf[4096];
  int c = blockIdx.x;            // 8 chunks across 2 arrays
  int base = c * 4096;
  int abase = (c & 3) * 4096;    // index within its own 16384 array
  for (int t = threadIdx.x; t < 4096; t += 1024) buf[t] = comp[base + t];
  __syncthreads();
  for (int k = 2; k <= 4096; k <<= 1){
    for (int j = k >> 1; j > 0; j >>= 1){
      for (int idx = threadIdx.x; idx < 2048; idx += 1024){
        int i = ((idx & ~(j-1)) << 1) | (idx & (j-1));
        int pi = i | j;
        bool dir = (((abase + i) & k) == 0);
        uint64_t A = buf[i], Bv = buf[pi];
        bool sw = dir ? (A > Bv) : (A < Bv);
        if (sw){ buf[i] = Bv; buf[pi] = A; }
      }
      __syncthreads();
    }
  }
  for (int t = threadIdx.x; t < 4096; t += 1024) comp[base + t] = buf[t];
}

__global__ void k_sort_global(uint64_t* comp, int k, int j){
  int t = blockIdx.x*blockDim.x + threadIdx.x;
  if (t >= NPTS) return;            // 8192 pairs per array * 2 arrays
  int a = t >> 13;
  int idx = t & 8191;
  int i = ((idx & ~(j-1)) << 1) | (idx & (j-1));
  int pi = i | j;
  bool dir = ((i & k) == 0);
  uint64_t* arr = comp + (size_t)a * NPTS;
  uint64_t A = arr[i], Bv = arr[pi];
  bool sw = dir ? (A > Bv) : (A < Bv);
  if (sw){ arr[i] = Bv; arr[pi] = A; }
}

__global__ __launch_bounds__(1024) void k_sort_finish(uint64_t* comp, int k){
  __shared__ uint64_t buf[4096];
  int c = blockIdx.x;
  int base = c * 4096;
  int abase = (c & 3) * 4096;
  for (int t = threadIdx.x; t < 4096; t += 1024) buf[t] = comp[base + t];
  __syncthreads();
  for (int j = 2048; j > 0; j >>= 1){
    for (int idx = threadIdx.x; idx < 2048; idx += 1024){
      int i = ((idx & ~(j-1)) << 1) | (idx & (j-1));
      int pi = i | j;
      bool dir = (((abase + i) & k) == 0);
      uint64_t A = buf[i], Bv = buf[pi];
      bool sw = dir ? (A > Bv) : (A < Bv);
      if (sw){ buf[i] = Bv; buf[pi] = A; }
    }
    __syncthreads();
  }
  for (int t = threadIdx.x; t < 4096; t += 1024) comp[base + t] = buf[t];
}

__global__ void k_gather(const uint64_t* comp, const float* source, const float* target,
                         float* src_sub, float* tgt_sub){
  int t = blockIdx.x*blockDim.x + threadIdx.x;
  if (t >= 2*NB*SS) return;
  int a = t / (NB*SS);
  int r = t % (NB*SS);
  int b = r / SS;
  int s2 = r % SS;
  int val = (int)(comp[(size_t)a*NPTS + s2] & 0x3FFFull);
  const float* inp = a ? target : source;
  float* outp = a ? tgt_sub : src_sub;
  for (int d = 0; d < 3; ++d)
    outp[((size_t)b*SS + s2)*3 + d] = inp[((size_t)b*NPTS + val)*3 + d];
}

// ---------------- sample + eval: 4-wave work-constant split-range ----------------
// 256 thr/candidate (4 waves = 25 waves/CU). Lane l of wave w owns points
// {l,l+64,l+128,l+192} (4 x's + 4 y's in regs, 8 min chains); wave w iterates
// t in [64w,64w+64). Same total VALU and LDS reads as r13; TLP doubled.
__global__ __launch_bounds__(256) void k_se(uint32_t ka, uint32_t kb,
    const float* __restrict__ mean, const float* __restrict__ sigma,
    const float* __restrict__ src_sub, const float* __restrict__ tgt_sub,
    float* __restrict__ z_buf, float* __restrict__ off_buf,
    float* __restrict__ fit){
  int c = blockIdx.x;
  int b = c / POPP;
  int tid = threadIdx.x;
  int wave = tid >> 6;
  int lane = tid & 63;
  __shared__ float qoff[6];
  __shared__ float4 ysd[SS];     // (-2Y, |Y|^2)
  __shared__ float4 xsd[SS];     // (-2PX, |PX|^2) transformed
  __shared__ float rmp[4][SS];   // per-wave rmin partials
  __shared__ float cmp[4][SS];   // per-wave cmin partials
  __shared__ float wpart[4];

  // ---- inline sampling (bitwise-identical trajectory) ----
  if (tid < 6){
    int i = c*6 + tid;
    uint32_t o0,o1; tf2x32(ka, kb, 0u, (uint32_t)i, o0, o1);
    uint32_t bits = o0 ^ o1;
    float u = __uint_as_float((bits >> 9) | 0x3F800000u) - 1.0f;
    u = u * 2.0f + ULOW;
    u = fmaxf(ULOW, u);
    float zz = SQRT2F * erfinv32(u);
    float m = mean[b*6 + tid], sg = sigma[b*6 + tid];
    float v = fmaf(sg, zz, m);
    float lim = (tid < 3) ? ROTF : 1.0f;
    v = fminf(fmaxf(v, -lim), lim);
    z_buf[i] = zz; off_buf[i] = v; qoff[tid] = v;
  }
  __syncthreads();

  float R[9];
  axisangle_R(qoff[0], qoff[1], qoff[2], R);
  float tx=qoff[3], ty=qoff[4], tz=qoff[5];

  // ---- stage Y: (-2Y, sy), 1 per thread ----
  {
    const float* tp = tgt_sub + ((size_t)b*SS + tid)*3;
    float Y0=tp[0], Y1=tp[1], Y2=tp[2];
    float sy = fmaf(Y2,Y2, fmaf(Y1,Y1, Y0*Y0));
    ysd[tid] = make_float4(-2.0f*Y0, -2.0f*Y1, -2.0f*Y2, sy);
  }
  // ---- transform + stage X: 1 per thread ----
  {
    const float* sp = src_sub + ((size_t)b*SS + tid)*3;
    float X0=sp[0], X1=sp[1], X2=sp[2];
    float px = fmaf(X2, R[2], fmaf(X1, R[1], X0*R[0])) + tx;
    float py = fmaf(X2, R[5], fmaf(X1, R[4], X0*R[3])) + ty;
    float pz = fmaf(X2, R[8], fmaf(X1, R[7], X0*R[6])) + tz;
    float sx = fmaf(pz,pz, fmaf(py,py, px*px));
    xsd[tid] = make_float4(-2.0f*px, -2.0f*py, -2.0f*pz, sx);
  }
  __syncthreads();

  // ---- own 4 x's and 4 y's into registers (exact: -0.5*(-2v) == v) ----
  float pxj[4],pyj[4],pzj[4];
  float yxj[4],yyj[4],yzj[4];
  #pragma unroll
  for (int j = 0; j < 4; ++j){
    int i = lane + 64*j;
    float4 xv = xsd[i];
    pxj[j] = -0.5f*xv.x; pyj[j] = -0.5f*xv.y; pzj[j] = -0.5f*xv.z;
    float4 yv = ysd[i];
    yxj[j] = -0.5f*yv.x; yyj[j] = -0.5f*yv.y; yzj[j] = -0.5f*yv.z;
  }

  // ---- split-range fused pass: wave w covers t in [w*64, w*64+64) ----
  float rm0=INFINITY, rm1=INFINITY, rm2=INFINITY, rm3=INFINITY;
  float cm0=INFINITY, cm1=INFINITY, cm2=INFINITY, cm3=INFINITY;
  int tbeg = wave*64;
  #pragma unroll 8
  for (int t = tbeg; t < tbeg+64; ++t){
    float4 yv = ysd[t];
    float4 xv = xsd[t];
    rm0 = fminf(rm0, fmaf(pxj[0], yv.x, fmaf(pyj[0], yv.y, fmaf(pzj[0], yv.z, yv.w))));
    rm1 = fminf(rm1, fmaf(pxj[1], yv.x, fmaf(pyj[1], yv.y, fmaf(pzj[1], yv.z, yv.w))));
    rm2 = fminf(rm2, fmaf(pxj[2], yv.x, fmaf(pyj[2], yv.y, fmaf(pzj[2], yv.z, yv.w))));
    rm3 = fminf(rm3, fmaf(pxj[3], yv.x, fmaf(pyj[3], yv.y, fmaf(pzj[3], yv.z, yv.w))));
    cm0 = fminf(cm0, fmaf(yxj[0], xv.x, fmaf(yyj[0], xv.y, fmaf(yzj[0], xv.z, xv.w))));
    cm1 = fminf(cm1, fmaf(yxj[1], xv.x, fmaf(yyj[1], xv.y, fmaf(yzj[1], xv.z, xv.w))));
    cm2 = fminf(cm2, fmaf(yxj[2], xv.x, fmaf(yyj[2], xv.y, fmaf(yzj[2], xv.z, xv.w))));
    cm3 = fminf(cm3, fmaf(yxj[3], xv.x, fmaf(yyj[3], xv.y, fmaf(yzj[3], xv.z, xv.w))));
  }

  rmp[wave][lane+  0] = rm0;  cmp[wave][lane+  0] = cm0;
  rmp[wave][lane+ 64] = rm1;  cmp[wave][lane+ 64] = cm1;
  rmp[wave][lane+128] = rm2;  cmp[wave][lane+128] = cm2;
  rmp[wave][lane+192] = rm3;  cmp[wave][lane+192] = cm3;
  __syncthreads();

  // ---- combine: thread tid finalizes point tid (both sides) ----
  float fx = xsd[tid].w + fminf(fminf(rmp[0][tid], rmp[1][tid]),
                                fminf(rmp[2][tid], rmp[3][tid]));
  float fy = ysd[tid].w + fminf(fminf(cmp[0][tid], cmp[1][tid]),
                                fminf(cmp[2][tid], cmp[3][tid]));
  float acc = fx + fy;

  for (int m = 32; m > 0; m >>= 1) acc += __shfl_xor(acc, m, 64);
  if (lane == 0) wpart[wave] = acc;
  __syncthreads();
  if (tid == 0) fit[c] = (((wpart[0]+wpart[1])+wpart[2])+wpart[3]) * (1.0f/256.0f);
}

// ---------------- chamfer fitness for the final mean (r9 version, 1 dispatch) ----------------
__global__ __launch_bounds__(128) void k_eval(const float* __restrict__ pos, int Pn,
    const float* __restrict__ src_sub, const float* __restrict__ tgt_sub,
    float* __restrict__ fit){
  int c = blockIdx.x;
  int b = c / Pn;
  int tid = threadIdx.x;
  int wave = tid >> 6;
  int lane = tid & 63;
  __shared__ float4 ysd[SS];
  __shared__ float4 xsd[SS];
  __shared__ float wpart[2];

  const float* q = pos + (size_t)c*6;
  float R[9];
  axisangle_R(q[0], q[1], q[2], R);
  float tx=q[3], ty=q[4], tz=q[5];

  for (int i = tid; i < SS; i += 128){
    const float* tp = tgt_sub + ((size_t)b*SS + i)*3;
    float Y0=tp[0], Y1=tp[1], Y2=tp[2];
    float sy = fmaf(Y2,Y2, fmaf(Y1,Y1, Y0*Y0));
    ysd[i] = make_float4(-2.0f*Y0, -2.0f*Y1, -2.0f*Y2, sy);
  }

  int xi0 = wave*128 + lane;
  int xi1 = xi0 + 64;
  float px0,py0,pz0,sx0, px1,py1,pz1,sx1;
  {
    const float* sp = src_sub + ((size_t)b*SS + xi0)*3;
    float X0=sp[0], X1=sp[1], X2=sp[2];
    px0 = fmaf(X2, R[2], fmaf(X1, R[1], X0*R[0])) + tx;
    py0 = fmaf(X2, R[5], fmaf(X1, R[4], X0*R[3])) + ty;
    pz0 = fmaf(X2, R[8], fmaf(X1, R[7], X0*R[6])) + tz;
    sx0 = fmaf(pz0,pz0, fmaf(py0,py0, px0*px0));
    xsd[xi0] = make_float4(-2.0f*px0, -2.0f*py0, -2.0f*pz0, sx0);
  }
  {
    const float* sp = src_sub + ((size_t)b*SS + xi1)*3;
    float X0=sp[0], X1=sp[1], X2=sp[2];
    px1 = fmaf(X2, R[2], fmaf(X1, R[1], X0*R[0])) + tx;
    py1 = fmaf(X2, R[5], fmaf(X1, R[4], X0*R[3])) + ty;
    pz1 = fmaf(X2, R[8], fmaf(X1, R[7], X0*R[6])) + tz;
    sx1 = fmaf(pz1,pz1, fmaf(py1,py1, px1*px1));
    xsd[xi1] = make_float4(-2.0f*px1, -2.0f*py1, -2.0f*pz1, sx1);
  }
  __syncthreads();

  float rm0 = INFINITY, rm1 = INFINITY;
  #pragma unroll 8
  for (int t = 0; t < SS; ++t){
    float4 yv = ysd[t];
    rm0 = fminf(rm0, fmaf(px0, yv.x, fmaf(py0, yv.y, fmaf(pz0, yv.z, yv.w))));
    rm1 = fminf(rm1, fmaf(px1, yv.x, fmaf(py1, yv.y, fmaf(pz1, yv.z, yv.w))));
  }
  float acc = (sx0 + rm0) + (sx1 + rm1);

  float4 yv0 = ysd[xi0];
  float4 yv1 = ysd[xi1];
  float yx0 = -0.5f*yv0.x, yy0 = -0.5f*yv0.y, yz0 = -0.5f*yv0.z, sy0 = yv0.w;
  float yx1 = -0.5f*yv1.x, yy1 = -0.5f*yv1.y, yz1 = -0.5f*yv1.z, sy1 = yv1.w;
  float cm0 = INFINITY, cm1 = INFINITY;
  #pragma unroll 8
  for (int t = 0; t < SS; ++t){
    float4 xv = xsd[t];
    cm0 = fminf(cm0, fmaf(yx0, xv.x, fmaf(yy0, xv.y, fmaf(yz0, xv.z, xv.w))));
    cm1 = fminf(cm1, fmaf(yx1, xv.x, fmaf(yy1, xv.y, fmaf(yz1, xv.z, xv.w))));
  }
  acc += (sy0 + cm0) + (sy1 + cm1);

  for (int m = 32; m > 0; m >>= 1) acc += __shfl_xor(acc, m, 64);
  if (lane == 0) wpart[wave] = acc;
  __syncthreads();
  if (tid == 0) fit[c] = (wpart[0] + wpart[1]) * (1.0f/256.0f);
}

// ---------------- selection + update (round-5 verbatim) ----------------
__global__ __launch_bounds__(64) void k_update(const float* __restrict__ fit,
    const float* __restrict__ off, const float* __restrict__ z,
    float* mean, float* sigma, float* gbest_pos, float* gbest_fit, WArr W){
  int b = blockIdx.x;
  int tid = threadIdx.x;
  __shared__ float lfit[POPP];
  __shared__ int order[POPP];
  __shared__ float mn[6], mz[6];
  if (tid < POPP) lfit[tid] = fit[b*POPP + tid];
  __syncthreads();
  if (tid < POPP){
    float f = lfit[tid];
    int r = 0;
    for (int j = 0; j < POPP; ++j){
      float fj = lfit[j];
      r += (fj < f) || (fj == f && j < tid);   // stable ascending rank
    }
    order[r] = tid;
  }
  __syncthreads();
  if (tid < 6){
    float a = 0.0f, bz = 0.0f;
    for (int m = 0; m < MUU; ++m){
      int idx = order[m];
      a  = fmaf(W.w[m], off[((size_t)b*POPP + idx)*6 + tid], a);
      bz = fmaf(W.w[m], z  [((size_t)b*POPP + idx)*6 + tid], bz);
    }
    mn[tid] = a; mz[tid] = bz;
  }
  __syncthreads();
  if (tid == 0){
    float avg = (((((fabsf(mz[0])+fabsf(mz[1]))+fabsf(mz[2]))+fabsf(mz[3]))+fabsf(mz[4]))+fabsf(mz[5])) / 6.0f;
    float e = expf(0.3f * (avg - 1.0f));
    for (int d = 0; d < 6; ++d){
      float sN = sigma[b*6 + d] * e;
      float lo = (d < 3) ? SLOR : SLOT;
      float hi = (d < 3) ? SHIR : SHIT;
      sN = fminf(fmaxf(sN, lo), hi);
      sigma[b*6 + d] = sN;
      mean[b*6 + d] = mn[d];
    }
    int i0 = order[0];
    float bf = lfit[i0];
    if (bf < gbest_fit[b]){
      gbest_fit[b] = bf;
      for (int d = 0; d < 6; ++d) gbest_pos[b*6 + d] = off[((size_t)b*POPP + i0)*6 + d];
    }
  }
}

// ---------------- finalize: choose gbest vs mean, emit R,t ----------------
__global__ void k_finalize(const float* mean, const float* mean_fit,
                           const float* gbest_pos, const float* gbest_fit, float* out){
  int b = blockIdx.x;
  if (threadIdx.x != 0) return;
  bool um = mean_fit[b] < gbest_fit[b];
  float g[6];
  for (int d = 0; d < 6; ++d) g[d] = um ? mean[b*6 + d] : gbest_pos[b*6 + d];
  float R[9];
  axisangle_R(g[0], g[1], g[2], R);
  for (int i = 0; i < 9; ++i) out[b*9 + i] = R[i];
  for (int d = 0; d < 3; ++d) out[NB*9 + b*3 + d] = g[3 + d];
}

__global__ void k_aligned(const float* __restrict__ src, const float* __restrict__ out_rt,
                          float* __restrict__ aligned){
  int idx = blockIdx.x*blockDim.x + threadIdx.x;
  if (idx >= NB*NPTS) return;
  int b = idx / NPTS;
  const float* R = out_rt + b*9;
  const float* t = out_rt + NB*9 + b*3;
  const float* p = src + (size_t)idx*3;
  float X0=p[0], X1=p[1], X2=p[2];
  float* o = aligned + (size_t)idx*3;
  o[0] = fmaf(X2, R[2], fmaf(X1, R[1], X0*R[0])) + t[0];
  o[1] = fmaf(X2, R[5], fmaf(X1, R[4], X0*R[3])) + t[1];
  o[2] = fmaf(X2, R[8], fmaf(X1, R[7], X0*R[6])) + t[2];
}

// ---------------- host ----------------
struct HKey { uint32_t a, b; };
static inline HKey h_tf(HKey k, uint32_t x0, uint32_t x1){
  uint32_t o0,o1; tf2x32(k.a, k.b, x0, x1, o0, o1);
  return {o0, o1};
}

static void run_sort(uint64_t* comp, hipStream_t stream){
  hipLaunchKernelGGL(k_sort_local,  dim3(8),  dim3(1024), 0, stream, comp);
  hipLaunchKernelGGL(k_sort_global, dim3(64), dim3(256),  0, stream, comp, 8192, 4096);
  hipLaunchKernelGGL(k_sort_finish, dim3(8),  dim3(1024), 0, stream, comp, 8192);
  hipLaunchKernelGGL(k_sort_global, dim3(64), dim3(256),  0, stream, comp, 16384, 8192);
  hipLaunchKernelGGL(k_sort_global, dim3(64), dim3(256),  0, stream, comp, 16384, 4096);
  hipLaunchKernelGGL(k_sort_finish, dim3(8),  dim3(1024), 0, stream, comp, 16384);
}

extern "C" void kernel_launch(void* const* d_in, const int* in_sizes, int n_in,
                              void* d_out, int out_size, void* d_ws, size_t ws_size,
                              hipStream_t stream){
  const float* source = (const float*)d_in[0];
  const float* target = (const float*)d_in[1];
  float* out = (float*)d_out;

  // ---- workspace layout (256B aligned chunks) ----
  uint8_t* w = (uint8_t*)d_ws;
  size_t o = 0;
  auto alloc = [&](size_t bytes){ void* p = w + o; o += (bytes + 255) & ~(size_t)255; return p; };
  uint64_t* comp   = (uint64_t*)alloc(2*(size_t)NPTS*8);
  float* src_sub   = (float*)alloc((size_t)NB*SS*3*4);
  float* tgt_sub   = (float*)alloc((size_t)NB*SS*3*4);
  float* z_buf     = (float*)alloc((size_t)NB*POPP*6*4);
  float* off_buf   = (float*)alloc((size_t)NB*POPP*6*4);
  float* fit_buf   = (float*)alloc((size_t)NB*POPP*4);
  float* mean_buf  = (float*)alloc((size_t)NB*6*4);
  float* sigma_buf = (float*)alloc((size_t)NB*6*4);
  float* gb_pos    = (float*)alloc((size_t)NB*6*4);
  float* gb_fit    = (float*)alloc((size_t)NB*4);
  float* mean_fit  = (float*)alloc((size_t)NB*4);
  (void)ws_size; (void)in_sizes; (void)n_in; (void)out_size;

  // ---- host-side JAX key derivation (threefry, partitionable mode) ----
  HKey key0 = {0u, 42u};
  HKey k1 = h_tf(key0, 0u, 0u);
  HKey k2 = h_tf(key0, 0u, 1u);
  HKey k3 = h_tf(key0, 0u, 2u);
  HKey srcA  = h_tf(k1, 0u, 0u);
  HKey srcS1 = h_tf(k1, 0u, 1u);
  HKey srcS2 = h_tf(srcA, 0u, 1u);
  HKey tgtA  = h_tf(k2, 0u, 0u);
  HKey tgtS1 = h_tf(k2, 0u, 1u);
  HKey tgtS2 = h_tf(tgtA, 0u, 1u);
  HKey itk[NITERS];
  for (int j = 0; j < NITERS; ++j) itk[j] = h_tf(k3, 0u, (uint32_t)j);

  // ---- recombination weights (numpy double math, cast f32) ----
  WArr W;
  {
    double lw[MUU], s = 0.0;
    for (int m = 0; m < MUU; ++m){ lw[m] = log((double)MUU + 0.5) - log((double)(m+1)); s += lw[m]; }
    for (int m = 0; m < MUU; ++m) W.w[m] = (float)(lw[m] / s);
  }

  hipLaunchKernelGGL(k_init, dim3(1), dim3(256), 0, stream, mean_buf, sigma_buf, gb_pos, gb_fit);

  // ---- permutations (2 stable-sort rounds each, both arrays together) ----
  hipLaunchKernelGGL(k_genperm, dim3(128), dim3(256), 0, stream,
                     comp, srcS1.a, srcS1.b, tgtS1.a, tgtS1.b, 0);
  run_sort(comp, stream);
  hipLaunchKernelGGL(k_genperm, dim3(128), dim3(256), 0, stream,
                     comp, srcS2.a, srcS2.b, tgtS2.a, tgtS2.b, 1);
  run_sort(comp, stream);
  hipLaunchKernelGGL(k_gather, dim3(64), dim3(256), 0, stream,
                     comp, source, target, src_sub, tgt_sub);

  // ---- CMA-ES main loop: sample+eval fused, update separate ----
  for (int it = 0; it < NITERS; ++it){
    hipLaunchKernelGGL(k_se, dim3(NB*POPP), dim3(256), 0, stream,
                       itk[it].a, itk[it].b, mean_buf, sigma_buf,
                       src_sub, tgt_sub, z_buf, off_buf, fit_buf);
    hipLaunchKernelGGL(k_update, dim3(NB), dim3(64), 0, stream,
                       fit_buf, off_buf, z_buf, mean_buf, sigma_buf, gb_pos, gb_fit, W);
  }

  // ---- final mean evaluation + output ----
  hipLaunchKernelGGL(k_eval, dim3(NB), dim3(128), 0, stream,
                     mean_buf, 1, src_sub, tgt_sub, mean_fit);
  hipLaunchKernelGGL(k_finalize, dim3(NB), dim3(64), 0, stream,
                     mean_buf, mean_fit, gb_pos, gb_fit, out);
  hipLaunchKernelGGL(k_aligned, dim3((NB*NPTS + 255)/256), dim3(256), 0, stream,
                     source, out, out + NB*9 + NB*3);
}

// Round 15
// 893.211 us; speedup vs baseline: 1.1391x; 1.0636x over previous
//
#include <hip/hip_runtime.h>
#include <stdint.h>
#include <math.h>

#define NB 32
#define NPTS 16384
#define SS 256
#define POPP 50
#define MUU 25
#define NITERS 30

#define ROTF  ((float)0.7853981633974483)
#define SIG0R ((float)(0.7853981633974483*0.3))
#define SIG0T ((float)0.3)
#define SLOR  ((float)(0.7853981633974483*0.01))
#define SHIR  ((float)(0.7853981633974483*0.5))
#define SLOT  ((float)0.01)
#define SHIT  ((float)0.5)
#define SQRT2F ((float)1.4142135623730951)
#define ULOW  (-0.99999994f)

// ---------------- threefry2x32 (JAX-exact) ----------------
__host__ __device__ inline uint32_t rotl32(uint32_t v, int n){ return (v<<n)|(v>>(32-n)); }

__host__ __device__ inline void tf2x32(uint32_t k0, uint32_t k1, uint32_t x0, uint32_t x1,
                                       uint32_t &o0, uint32_t &o1){
  uint32_t ks2 = k0 ^ k1 ^ 0x1BD11BDAu;
  x0 += k0; x1 += k1;
#define TFR(r) { x0 += x1; x1 = rotl32(x1, r); x1 ^= x0; }
  TFR(13) TFR(15) TFR(26) TFR(6)
  x0 += k1; x1 += ks2 + 1u;
  TFR(17) TFR(29) TFR(16) TFR(24)
  x0 += ks2; x1 += k0 + 2u;
  TFR(13) TFR(15) TFR(26) TFR(6)
  x0 += k0; x1 += k1 + 3u;
  TFR(17) TFR(29) TFR(16) TFR(24)
  x0 += k1; x1 += ks2 + 4u;
  TFR(13) TFR(15) TFR(26) TFR(6)
  x0 += ks2; x1 += k0 + 5u;
#undef TFR
  o0 = x0; o1 = x1;
}

// XLA ErfInv32 (Giles), exact coefficients
__device__ inline float erfinv32(float x){
  float w = -log1pf(-x*x);
  float p;
  if (w < 5.0f) {
    w = w - 2.5f;
    p = 2.81022636e-08f;
    p = fmaf(p, w, 3.43273939e-07f);
    p = fmaf(p, w, -3.5233877e-06f);
    p = fmaf(p, w, -4.39150654e-06f);
    p = fmaf(p, w, 0.00021858087f);
    p = fmaf(p, w, -0.00125372503f);
    p = fmaf(p, w, -0.00417768164f);
    p = fmaf(p, w, 0.246640727f);
    p = fmaf(p, w, 1.50140941f);
  } else {
    w = sqrtf(w) - 3.0f;
    p = -0.000200214257f;
    p = fmaf(p, w, 0.000100950558f);
    p = fmaf(p, w, 0.00134934322f);
    p = fmaf(p, w, -0.00367342844f);
    p = fmaf(p, w, 0.00573950773f);
    p = fmaf(p, w, -0.0076224613f);
    p = fmaf(p, w, 0.00943887047f);
    p = fmaf(p, w, 1.00167406f);
    p = fmaf(p, w, 2.83297682f);
  }
  return p * x;
}

__device__ inline void axisangle_R(float ax, float ay, float az, float R[9]){
  float th = sqrtf(ax*ax + ay*ay + az*az);
  float den = th + 1e-8f;
  float ux = ax/den, uy = ay/den, uz = az/den;
  float s = sinf(th), c = cosf(th);
  float omc = 1.0f - c;
  float xx=ux*ux, yy=uy*uy, zz=uz*uz;
  float xy=ux*uy, xz=ux*uz, yz=uy*uz;
  R[0] = 1.0f + omc*(-(yy+zz));
  R[1] = s*(-uz) + omc*xy;
  R[2] = s*uy    + omc*xz;
  R[3] = s*uz    + omc*xy;
  R[4] = 1.0f + omc*(-(xx+zz));
  R[5] = s*(-ux) + omc*yz;
  R[6] = s*(-uy) + omc*xz;
  R[7] = s*ux    + omc*yz;
  R[8] = 1.0f + omc*(-(xx+yy));
}

struct WArr { float w[MUU]; };

// ---------------- init (parity-0 state) ----------------
__global__ void k_init(float* mean, float* sigma, float* gbest_pos, float* gbest_fit){
  int i = blockIdx.x*blockDim.x + threadIdx.x;
  if (i < NB*6){
    mean[i] = 0.0f;
    gbest_pos[i] = 0.0f;
    int d = i % 6;
    sigma[i] = (d < 3) ? SIG0R : SIG0T;
  }
  if (i < NB) gbest_fit[i] = INFINITY;
}

// ---------------- permutation sort-keys gen ----------------
__global__ void k_genperm(uint64_t* comp, uint32_t sa0, uint32_t sa1,
                          uint32_t sb0, uint32_t sb1, int round){
  int i = blockIdx.x*blockDim.x + threadIdx.x;
  if (i >= 2*NPTS) return;
  int a = i >> 14;
  int idx = i & (NPTS-1);
  uint32_t kk0 = a ? sb0 : sa0;
  uint32_t kk1 = a ? sb1 : sa1;
  uint32_t o0,o1; tf2x32(kk0, kk1, 0u, (uint32_t)idx, o0, o1);
  uint32_t key = o0 ^ o1;
  uint64_t val = (round == 0) ? (uint64_t)idx : (comp[i] & 0x3FFFull);
  comp[i] = ((uint64_t)key << 28) | ((uint64_t)idx << 14) | val;
}

// ---------------- bitonic sort (ascending by u64) ----------------
__global__ __launch_bounds__(1024) void k_sort_local(uint64_t* comp){
  __shared__ uint64_t buf[4096];
  int c = blockIdx.x;
  int base = c * 4096;
  int abase = (c & 3) * 4096;
  for (int t = threadIdx.x; t < 4096; t += 1024) buf[t] = comp[base + t];
  __syncthreads();
  for (int k = 2; k <= 4096; k <<= 1){
    for (int j = k >> 1; j > 0; j >>= 1){
      for (int idx = threadIdx.x; idx < 2048; idx += 1024){
        int i = ((idx & ~(j-1)) << 1) | (idx & (j-1));
        int pi = i | j;
        bool dir = (((abase + i) & k) == 0);
        uint64_t A = buf[i], Bv = buf[pi];
        bool sw = dir ? (A > Bv) : (A < Bv);
        if (sw){ buf[i] = Bv; buf[pi] = A; }
      }
      __syncthreads();
    }
  }
  for (int t = threadIdx.x; t < 4096; t += 1024) comp[base + t] = buf[t];
}

__global__ void k_sort_global(uint64_t* comp, int k, int j){
  int t = blockIdx.x*blockDim.x + threadIdx.x;
  if (t >= NPTS) return;
  int a = t >> 13;
  int idx = t & 8191;
  int i = ((idx & ~(j-1)) << 1) | (idx & (j-1));
  int pi = i | j;
  bool dir = ((i & k) == 0);
  uint64_t* arr = comp + (size_t)a * NPTS;
  uint64_t A = arr[i], Bv = arr[pi];
  bool sw = dir ? (A > Bv) : (A < Bv);
  if (sw){ arr[i] = Bv; arr[pi] = A; }
}

__global__ __launch_bounds__(1024) void k_sort_finish(uint64_t* comp, int k){
  __shared__ uint64_t buf[4096];
  int c = blockIdx.x;
  int base = c * 4096;
  int abase = (c & 3) * 4096;
  for (int t = threadIdx.x; t < 4096; t += 1024) buf[t] = comp[base + t];
  __syncthreads();
  for (int j = 2048; j > 0; j >>= 1){
    for (int idx = threadIdx.x; idx < 2048; idx += 1024){
      int i = ((idx & ~(j-1)) << 1) | (idx & (j-1));
      int pi = i | j;
      bool dir = (((abase + i) & k) == 0);
      uint64_t A = buf[i], Bv = buf[pi];
      bool sw = dir ? (A > Bv) : (A < Bv);
      if (sw){ buf[i] = Bv; buf[pi] = A; }
    }
    __syncthreads();
  }
  for (int t = threadIdx.x; t < 4096; t += 1024) comp[base + t] = buf[t];
}

__global__ void k_gather(const uint64_t* comp, const float* source, const float* target,
                         float* src_sub, float* tgt_sub){
  int t = blockIdx.x*blockDim.x + threadIdx.x;
  if (t >= 2*NB*SS) return;
  int a = t / (NB*SS);
  int r = t % (NB*SS);
  int b = r / SS;
  int s2 = r % SS;
  int val = (int)(comp[(size_t)a*NPTS + s2] & 0x3FFFull);
  const float* inp = a ? target : source;
  float* outp = a ? tgt_sub : src_sub;
  for (int d = 0; d < 3; ++d)
    outp[((size_t)b*SS + s2)*3 + d] = inp[((size_t)b*NPTS + val)*3 + d];
}

// ---------------- fused iteration: redundant update-prologue + sample + eval ----------------
// Every block of batch b recomputes iteration it-1's CMA-ES update (bitwise-identical
// across blocks -> benign same-value global writes), samples with the fresh mean/sigma,
// then runs the r14 4-wave split-range eval. Parity double-buffering on
// fit/z/off/mean/sigma removes all intra-kernel read/write hazards.
__global__ __launch_bounds__(256) void k_se(uint32_t ka, uint32_t kb, int it,
    float* __restrict__ mean_base, float* __restrict__ sigma_base,
    const float* __restrict__ src_sub, const float* __restrict__ tgt_sub,
    float* __restrict__ z_base, float* __restrict__ off_base,
    float* __restrict__ fit_base,
    float* __restrict__ gb_pos, float* __restrict__ gb_fit, WArr W){
  int c = blockIdx.x;
  int b = c / POPP;
  int tid = threadIdx.x;
  int wave = tid >> 6;
  int lane = tid & 63;

  int readP  = (it == 0) ? 0 : ((it-1)&1);
  int writeP = it & 1;
  const float* fitR = fit_base + readP*(NB*POPP);
  float*       fitW = fit_base + writeP*(NB*POPP);
  const float* zR   = z_base   + (size_t)readP*(NB*POPP*6);
  float*       zC   = z_base   + (size_t)writeP*(NB*POPP*6);
  const float* offR = off_base + (size_t)readP*(NB*POPP*6);
  float*       offC = off_base + (size_t)writeP*(NB*POPP*6);
  const float* sigR = sigma_base + readP*(NB*6);
  float*       sigW = sigma_base + writeP*(NB*6);
  const float* meanR = mean_base + readP*(NB*6);
  float*       meanW = mean_base + writeP*(NB*6);

  __shared__ float qmean[6], qsig[6];
  __shared__ float lfit[POPP];
  __shared__ int   order[POPP];
  __shared__ float mn[6], mzs[6];
  __shared__ float qoff[6];
  __shared__ float4 ysd[SS];
  __shared__ float4 xsd[SS];
  __shared__ float rmp[4][SS];
  __shared__ float cmp[4][SS];
  __shared__ float wpart[4];

  if (it > 0){
    // ---- redundant update recompute (identical in all blocks of batch b) ----
    if (tid < POPP) lfit[tid] = fitR[b*POPP + tid];
    __syncthreads();
    if (tid < POPP){
      float f = lfit[tid];
      int r = 0;
      for (int j = 0; j < POPP; ++j){
        float fj = lfit[j];
        r += (fj < f) || (fj == f && j < tid);   // stable ascending rank
      }
      order[r] = tid;
    }
    __syncthreads();
    if (tid < 6){
      float a = 0.0f, bz = 0.0f;
      for (int m = 0; m < MUU; ++m){
        int idx = order[m];
        a  = fmaf(W.w[m], offR[((size_t)b*POPP + idx)*6 + tid], a);
        bz = fmaf(W.w[m], zR [((size_t)b*POPP + idx)*6 + tid], bz);
      }
      mn[tid] = a; mzs[tid] = bz;
    }
    __syncthreads();
    if (tid == 0){
      float avg = (((((fabsf(mzs[0])+fabsf(mzs[1]))+fabsf(mzs[2]))+fabsf(mzs[3]))+fabsf(mzs[4]))+fabsf(mzs[5])) / 6.0f;
      float e = expf(0.3f * (avg - 1.0f));
      for (int d = 0; d < 6; ++d){
        float sN = sigR[b*6 + d] * e;
        float lo = (d < 3) ? SLOR : SLOT;
        float hi = (d < 3) ? SHIR : SHIT;
        sN = fminf(fmaxf(sN, lo), hi);
        qsig[d] = sN; sigW[b*6 + d] = sN;
        qmean[d] = mn[d]; meanW[b*6 + d] = mn[d];
      }
      int i0 = order[0];
      float bf = lfit[i0];
      if (bf < gb_fit[b]){
        gb_fit[b] = bf;
        for (int d = 0; d < 6; ++d) gb_pos[b*6 + d] = offR[((size_t)b*POPP + i0)*6 + d];
      }
    }
  } else {
    if (tid < 6){ qmean[tid] = meanR[b*6 + tid]; qsig[tid] = sigR[b*6 + tid]; }
  }
  __syncthreads();

  // ---- sampling (bitwise-identical trajectory) ----
  if (tid < 6){
    int i = c*6 + tid;
    uint32_t o0,o1; tf2x32(ka, kb, 0u, (uint32_t)i, o0, o1);
    uint32_t bits = o0 ^ o1;
    float u = __uint_as_float((bits >> 9) | 0x3F800000u) - 1.0f;
    u = u * 2.0f + ULOW;
    u = fmaxf(ULOW, u);
    float zz = SQRT2F * erfinv32(u);
    float m = qmean[tid], sg = qsig[tid];
    float v = fmaf(sg, zz, m);
    float lim = (tid < 3) ? ROTF : 1.0f;
    v = fminf(fmaxf(v, -lim), lim);
    zC[i] = zz; offC[i] = v; qoff[tid] = v;
  }
  __syncthreads();

  float R[9];
  axisangle_R(qoff[0], qoff[1], qoff[2], R);
  float tx=qoff[3], ty=qoff[4], tz=qoff[5];

  // ---- stage Y / transform+stage X: 1 per thread ----
  {
    const float* tp = tgt_sub + ((size_t)b*SS + tid)*3;
    float Y0=tp[0], Y1=tp[1], Y2=tp[2];
    float sy = fmaf(Y2,Y2, fmaf(Y1,Y1, Y0*Y0));
    ysd[tid] = make_float4(-2.0f*Y0, -2.0f*Y1, -2.0f*Y2, sy);
  }
  {
    const float* sp = src_sub + ((size_t)b*SS + tid)*3;
    float X0=sp[0], X1=sp[1], X2=sp[2];
    float px = fmaf(X2, R[2], fmaf(X1, R[1], X0*R[0])) + tx;
    float py = fmaf(X2, R[5], fmaf(X1, R[4], X0*R[3])) + ty;
    float pz = fmaf(X2, R[8], fmaf(X1, R[7], X0*R[6])) + tz;
    float sx = fmaf(pz,pz, fmaf(py,py, px*px));
    xsd[tid] = make_float4(-2.0f*px, -2.0f*py, -2.0f*pz, sx);
  }
  __syncthreads();

  // ---- own 4 x's and 4 y's into registers ----
  float pxj[4],pyj[4],pzj[4];
  float yxj[4],yyj[4],yzj[4];
  #pragma unroll
  for (int j = 0; j < 4; ++j){
    int i = lane + 64*j;
    float4 xv = xsd[i];
    pxj[j] = -0.5f*xv.x; pyj[j] = -0.5f*xv.y; pzj[j] = -0.5f*xv.z;
    float4 yv = ysd[i];
    yxj[j] = -0.5f*yv.x; yyj[j] = -0.5f*yv.y; yzj[j] = -0.5f*yv.z;
  }

  // ---- split-range fused pass: wave w covers t in [w*64, w*64+64) ----
  float rm0=INFINITY, rm1=INFINITY, rm2=INFINITY, rm3=INFINITY;
  float cm0=INFINITY, cm1=INFINITY, cm2=INFINITY, cm3=INFINITY;
  int tbeg = wave*64;
  #pragma unroll 8
  for (int t = tbeg; t < tbeg+64; ++t){
    float4 yv = ysd[t];
    float4 xv = xsd[t];
    rm0 = fminf(rm0, fmaf(pxj[0], yv.x, fmaf(pyj[0], yv.y, fmaf(pzj[0], yv.z, yv.w))));
    rm1 = fminf(rm1, fmaf(pxj[1], yv.x, fmaf(pyj[1], yv.y, fmaf(pzj[1], yv.z, yv.w))));
    rm2 = fminf(rm2, fmaf(pxj[2], yv.x, fmaf(pyj[2], yv.y, fmaf(pzj[2], yv.z, yv.w))));
    rm3 = fminf(rm3, fmaf(pxj[3], yv.x, fmaf(pyj[3], yv.y, fmaf(pzj[3], yv.z, yv.w))));
    cm0 = fminf(cm0, fmaf(yxj[0], xv.x, fmaf(yyj[0], xv.y, fmaf(yzj[0], xv.z, xv.w))));
    cm1 = fminf(cm1, fmaf(yxj[1], xv.x, fmaf(yyj[1], xv.y, fmaf(yzj[1], xv.z, xv.w))));
    cm2 = fminf(cm2, fmaf(yxj[2], xv.x, fmaf(yyj[2], xv.y, fmaf(yzj[2], xv.z, xv.w))));
    cm3 = fminf(cm3, fmaf(yxj[3], xv.x, fmaf(yyj[3], xv.y, fmaf(yzj[3], xv.z, xv.w))));
  }

  rmp[wave][lane+  0] = rm0;  cmp[wave][lane+  0] = cm0;
  rmp[wave][lane+ 64] = rm1;  cmp[wave][lane+ 64] = cm1;
  rmp[wave][lane+128] = rm2;  cmp[wave][lane+128] = cm2;
  rmp[wave][lane+192] = rm3;  cmp[wave][lane+192] = cm3;
  __syncthreads();

  float fx = xsd[tid].w + fminf(fminf(rmp[0][tid], rmp[1][tid]),
                                fminf(rmp[2][tid], rmp[3][tid]));
  float fy = ysd[tid].w + fminf(fminf(cmp[0][tid], cmp[1][tid]),
                                fminf(cmp[2][tid], cmp[3][tid]));
  float acc = fx + fy;

  for (int m = 32; m > 0; m >>= 1) acc += __shfl_xor(acc, m, 64);
  if (lane == 0) wpart[wave] = acc;
  __syncthreads();
  if (tid == 0) fitW[c] = (((wpart[0]+wpart[1])+wpart[2])+wpart[3]) * (1.0f/256.0f);
}

// ---------------- chamfer fitness for the final mean (r9 version, 1 dispatch) ----------------
__global__ __launch_bounds__(128) void k_eval(const float* __restrict__ pos, int Pn,
    const float* __restrict__ src_sub, const float* __restrict__ tgt_sub,
    float* __restrict__ fit){
  int c = blockIdx.x;
  int b = c / Pn;
  int tid = threadIdx.x;
  int wave = tid >> 6;
  int lane = tid & 63;
  __shared__ float4 ysd[SS];
  __shared__ float4 xsd[SS];
  __shared__ float wpart[2];

  const float* q = pos + (size_t)c*6;
  float R[9];
  axisangle_R(q[0], q[1], q[2], R);
  float tx=q[3], ty=q[4], tz=q[5];

  for (int i = tid; i < SS; i += 128){
    const float* tp = tgt_sub + ((size_t)b*SS + i)*3;
    float Y0=tp[0], Y1=tp[1], Y2=tp[2];
    float sy = fmaf(Y2,Y2, fmaf(Y1,Y1, Y0*Y0));
    ysd[i] = make_float4(-2.0f*Y0, -2.0f*Y1, -2.0f*Y2, sy);
  }

  int xi0 = wave*128 + lane;
  int xi1 = xi0 + 64;
  float px0,py0,pz0,sx0, px1,py1,pz1,sx1;
  {
    const float* sp = src_sub + ((size_t)b*SS + xi0)*3;
    float X0=sp[0], X1=sp[1], X2=sp[2];
    px0 = fmaf(X2, R[2], fmaf(X1, R[1], X0*R[0])) + tx;
    py0 = fmaf(X2, R[5], fmaf(X1, R[4], X0*R[3])) + ty;
    pz0 = fmaf(X2, R[8], fmaf(X1, R[7], X0*R[6])) + tz;
    sx0 = fmaf(pz0,pz0, fmaf(py0,py0, px0*px0));
    xsd[xi0] = make_float4(-2.0f*px0, -2.0f*py0, -2.0f*pz0, sx0);
  }
  {
    const float* sp = src_sub + ((size_t)b*SS + xi1)*3;
    float X0=sp[0], X1=sp[1], X2=sp[2];
    px1 = fmaf(X2, R[2], fmaf(X1, R[1], X0*R[0])) + tx;
    py1 = fmaf(X2, R[5], fmaf(X1, R[4], X0*R[3])) + ty;
    pz1 = fmaf(X2, R[8], fmaf(X1, R[7], X0*R[6])) + tz;
    sx1 = fmaf(pz1,pz1, fmaf(py1,py1, px1*px1));
    xsd[xi1] = make_float4(-2.0f*px1, -2.0f*py1, -2.0f*pz1, sx1);
  }
  __syncthreads();

  float rm0 = INFINITY, rm1 = INFINITY;
  #pragma unroll 8
  for (int t = 0; t < SS; ++t){
    float4 yv = ysd[t];
    rm0 = fminf(rm0, fmaf(px0, yv.x, fmaf(py0, yv.y, fmaf(pz0, yv.z, yv.w))));
    rm1 = fminf(rm1, fmaf(px1, yv.x, fmaf(py1, yv.y, fmaf(pz1, yv.z, yv.w))));
  }
  float acc = (sx0 + rm0) + (sx1 + rm1);

  float4 yv0 = ysd[xi0];
  float4 yv1 = ysd[xi1];
  float yx0 = -0.5f*yv0.x, yy0 = -0.5f*yv0.y, yz0 = -0.5f*yv0.z, sy0 = yv0.w;
  float yx1 = -0.5f*yv1.x, yy1 = -0.5f*yv1.y, yz1 = -0.5f*yv1.z, sy1 = yv1.w;
  float cm0 = INFINITY, cm1 = INFINITY;
  #pragma unroll 8
  for (int t = 0; t < SS; ++t){
    float4 xv = xsd[t];
    cm0 = fminf(cm0, fmaf(yx0, xv.x, fmaf(yy0, xv.y, fmaf(yz0, xv.z, xv.w))));
    cm1 = fminf(cm1, fmaf(yx1, xv.x, fmaf(yy1, xv.y, fmaf(yz1, xv.z, xv.w))));
  }
  acc += (sy0 + cm0) + (sy1 + cm1);

  for (int m = 32; m > 0; m >>= 1) acc += __shfl_xor(acc, m, 64);
  if (lane == 0) wpart[wave] = acc;
  __syncthreads();
  if (tid == 0) fit[c] = (wpart[0] + wpart[1]) * (1.0f/256.0f);
}

// ---------------- selection + update (final iteration only) ----------------
__global__ __launch_bounds__(64) void k_update(const float* __restrict__ fit,
    const float* __restrict__ off, const float* __restrict__ z,
    float* mean, float* sigma, float* gbest_pos, float* gbest_fit, WArr W){
  int b = blockIdx.x;
  int tid = threadIdx.x;
  __shared__ float lfit[POPP];
  __shared__ int order[POPP];
  __shared__ float mn[6], mz[6];
  if (tid < POPP) lfit[tid] = fit[b*POPP + tid];
  __syncthreads();
  if (tid < POPP){
    float f = lfit[tid];
    int r = 0;
    for (int j = 0; j < POPP; ++j){
      float fj = lfit[j];
      r += (fj < f) || (fj == f && j < tid);   // stable ascending rank
    }
    order[r] = tid;
  }
  __syncthreads();
  if (tid < 6){
    float a = 0.0f, bz = 0.0f;
    for (int m = 0; m < MUU; ++m){
      int idx = order[m];
      a  = fmaf(W.w[m], off[((size_t)b*POPP + idx)*6 + tid], a);
      bz = fmaf(W.w[m], z  [((size_t)b*POPP + idx)*6 + tid], bz);
    }
    mn[tid] = a; mz[tid] = bz;
  }
  __syncthreads();
  if (tid == 0){
    float avg = (((((fabsf(mz[0])+fabsf(mz[1]))+fabsf(mz[2]))+fabsf(mz[3]))+fabsf(mz[4]))+fabsf(mz[5])) / 6.0f;
    float e = expf(0.3f * (avg - 1.0f));
    for (int d = 0; d < 6; ++d){
      float sN = sigma[b*6 + d] * e;
      float lo = (d < 3) ? SLOR : SLOT;
      float hi = (d < 3) ? SHIR : SHIT;
      sN = fminf(fmaxf(sN, lo), hi);
      sigma[b*6 + d] = sN;
      mean[b*6 + d] = mn[d];
    }
    int i0 = order[0];
    float bf = lfit[i0];
    if (bf < gbest_fit[b]){
      gbest_fit[b] = bf;
      for (int d = 0; d < 6; ++d) gbest_pos[b*6 + d] = off[((size_t)b*POPP + i0)*6 + d];
    }
  }
}

// ---------------- finalize: choose gbest vs mean, emit R,t ----------------
__global__ void k_finalize(const float* mean, const float* mean_fit,
                           const float* gbest_pos, const float* gbest_fit, float* out){
  int b = blockIdx.x;
  if (threadIdx.x != 0) return;
  bool um = mean_fit[b] < gbest_fit[b];
  float g[6];
  for (int d = 0; d < 6; ++d) g[d] = um ? mean[b*6 + d] : gbest_pos[b*6 + d];
  float R[9];
  axisangle_R(g[0], g[1], g[2], R);
  for (int i = 0; i < 9; ++i) out[b*9 + i] = R[i];
  for (int d = 0; d < 3; ++d) out[NB*9 + b*3 + d] = g[3 + d];
}

__global__ void k_aligned(const float* __restrict__ src, const float* __restrict__ out_rt,
                          float* __restrict__ aligned){
  int idx = blockIdx.x*blockDim.x + threadIdx.x;
  if (idx >= NB*NPTS) return;
  int b = idx / NPTS;
  const float* R = out_rt + b*9;
  const float* t = out_rt + NB*9 + b*3;
  const float* p = src + (size_t)idx*3;
  float X0=p[0], X1=p[1], X2=p[2];
  float* o = aligned + (size_t)idx*3;
  o[0] = fmaf(X2, R[2], fmaf(X1, R[1], X0*R[0])) + t[0];
  o[1] = fmaf(X2, R[5], fmaf(X1, R[4], X0*R[3])) + t[1];
  o[2] = fmaf(X2, R[8], fmaf(X1, R[7], X0*R[6])) + t[2];
}

// ---------------- host ----------------
struct HKey { uint32_t a, b; };
static inline HKey h_tf(HKey k, uint32_t x0, uint32_t x1){
  uint32_t o0,o1; tf2x32(k.a, k.b, x0, x1, o0, o1);
  return {o0, o1};
}

static void run_sort(uint64_t* comp, hipStream_t stream){
  hipLaunchKernelGGL(k_sort_local,  dim3(8),  dim3(1024), 0, stream, comp);
  hipLaunchKernelGGL(k_sort_global, dim3(64), dim3(256),  0, stream, comp, 8192, 4096);
  hipLaunchKernelGGL(k_sort_finish, dim3(8),  dim3(1024), 0, stream, comp, 8192);
  hipLaunchKernelGGL(k_sort_global, dim3(64), dim3(256),  0, stream, comp, 16384, 8192);
  hipLaunchKernelGGL(k_sort_global, dim3(64), dim3(256),  0, stream, comp, 16384, 4096);
  hipLaunchKernelGGL(k_sort_finish, dim3(8),  dim3(1024), 0, stream, comp, 16384);
}

extern "C" void kernel_launch(void* const* d_in, const int* in_sizes, int n_in,
                              void* d_out, int out_size, void* d_ws, size_t ws_size,
                              hipStream_t stream){
  const float* source = (const float*)d_in[0];
  const float* target = (const float*)d_in[1];
  float* out = (float*)d_out;

  // ---- workspace layout (256B aligned chunks; parity-doubled state buffers) ----
  uint8_t* w = (uint8_t*)d_ws;
  size_t o = 0;
  auto alloc = [&](size_t bytes){ void* p = w + o; o += (bytes + 255) & ~(size_t)255; return p; };
  uint64_t* comp   = (uint64_t*)alloc(2*(size_t)NPTS*8);
  float* src_sub   = (float*)alloc((size_t)NB*SS*3*4);
  float* tgt_sub   = (float*)alloc((size_t)NB*SS*3*4);
  float* z_buf     = (float*)alloc(2*(size_t)NB*POPP*6*4);
  float* off_buf   = (float*)alloc(2*(size_t)NB*POPP*6*4);
  float* fit_buf   = (float*)alloc(2*(size_t)NB*POPP*4);
  float* mean_buf  = (float*)alloc(2*(size_t)NB*6*4);
  float* sigma_buf = (float*)alloc(2*(size_t)NB*6*4);
  float* gb_pos    = (float*)alloc((size_t)NB*6*4);
  float* gb_fit    = (float*)alloc((size_t)NB*4);
  float* mean_fit  = (float*)alloc((size_t)NB*4);
  (void)ws_size; (void)in_sizes; (void)n_in; (void)out_size;

  // ---- host-side JAX key derivation (threefry, partitionable mode) ----
  HKey key0 = {0u, 42u};
  HKey k1 = h_tf(key0, 0u, 0u);
  HKey k2 = h_tf(key0, 0u, 1u);
  HKey k3 = h_tf(key0, 0u, 2u);
  HKey srcA  = h_tf(k1, 0u, 0u);
  HKey srcS1 = h_tf(k1, 0u, 1u);
  HKey srcS2 = h_tf(srcA, 0u, 1u);
  HKey tgtA  = h_tf(k2, 0u, 0u);
  HKey tgtS1 = h_tf(k2, 0u, 1u);
  HKey tgtS2 = h_tf(tgtA, 0u, 1u);
  HKey itk[NITERS];
  for (int j = 0; j < NITERS; ++j) itk[j] = h_tf(k3, 0u, (uint32_t)j);

  // ---- recombination weights (numpy double math, cast f32) ----
  WArr W;
  {
    double lw[MUU], s = 0.0;
    for (int m = 0; m < MUU; ++m){ lw[m] = log((double)MUU + 0.5) - log((double)(m+1)); s += lw[m]; }
    for (int m = 0; m < MUU; ++m) W.w[m] = (float)(lw[m] / s);
  }

  hipLaunchKernelGGL(k_init, dim3(1), dim3(256), 0, stream, mean_buf, sigma_buf, gb_pos, gb_fit);

  // ---- permutations (2 stable-sort rounds each, both arrays together) ----
  hipLaunchKernelGGL(k_genperm, dim3(128), dim3(256), 0, stream,
                     comp, srcS1.a, srcS1.b, tgtS1.a, tgtS1.b, 0);
  run_sort(comp, stream);
  hipLaunchKernelGGL(k_genperm, dim3(128), dim3(256), 0, stream,
                     comp, srcS2.a, srcS2.b, tgtS2.a, tgtS2.b, 1);
  run_sort(comp, stream);
  hipLaunchKernelGGL(k_gather, dim3(64), dim3(256), 0, stream,
                     comp, source, target, src_sub, tgt_sub);

  // ---- CMA-ES main loop: ONE kernel per iteration (update fused as prologue) ----
  for (int it = 0; it < NITERS; ++it){
    hipLaunchKernelGGL(k_se, dim3(NB*POPP), dim3(256), 0, stream,
                       itk[it].a, itk[it].b, it, mean_buf, sigma_buf,
                       src_sub, tgt_sub, z_buf, off_buf, fit_buf,
                       gb_pos, gb_fit, W);
  }

  // ---- final (iteration-30) update on parity-1 state ----
  hipLaunchKernelGGL(k_update, dim3(NB), dim3(64), 0, stream,
                     fit_buf + NB*POPP, off_buf + (size_t)NB*POPP*6, z_buf + (size_t)NB*POPP*6,
                     mean_buf + NB*6, sigma_buf + NB*6, gb_pos, gb_fit, W);

  // ---- final mean evaluation + output ----
  hipLaunchKernelGGL(k_eval, dim3(NB), dim3(128), 0, stream,
                     mean_buf + NB*6, 1, src_sub, tgt_sub, mean_fit);
  hipLaunchKernelGGL(k_finalize, dim3(NB), dim3(64), 0, stream,
                     mean_buf + NB*6, mean_fit, gb_pos, gb_fit, out);
  hipLaunchKernelGGL(k_aligned, dim3((NB*NPTS + 255)/256), dim3(256), 0, stream,
                     source, out, out + NB*9 + NB*3);
}

// Round 17
// 844.803 us; speedup vs baseline: 1.2043x; 1.0573x over previous
//
#include <hip/hip_runtime.h>
#include <stdint.h>
#include <math.h>

#define NB 32
#define NPTS 16384
#define SS 256
#define POPP 50
#define MUU 25
#define NITERS 30

#define ROTF  ((float)0.7853981633974483)
#define SIG0R ((float)(0.7853981633974483*0.3))
#define SIG0T ((float)0.3)
#define SLOR  ((float)(0.7853981633974483*0.01))
#define SHIR  ((float)(0.7853981633974483*0.5))
#define SLOT  ((float)0.01)
#define SHIT  ((float)0.5)
#define SQRT2F ((float)1.4142135623730951)
#define ULOW  (-0.99999994f)

// ---------------- threefry2x32 (JAX-exact) ----------------
__host__ __device__ inline uint32_t rotl32(uint32_t v, int n){ return (v<<n)|(v>>(32-n)); }

__host__ __device__ inline void tf2x32(uint32_t k0, uint32_t k1, uint32_t x0, uint32_t x1,
                                       uint32_t &o0, uint32_t &o1){
  uint32_t ks2 = k0 ^ k1 ^ 0x1BD11BDAu;
  x0 += k0; x1 += k1;
#define TFR(r) { x0 += x1; x1 = rotl32(x1, r); x1 ^= x0; }
  TFR(13) TFR(15) TFR(26) TFR(6)
  x0 += k1; x1 += ks2 + 1u;
  TFR(17) TFR(29) TFR(16) TFR(24)
  x0 += ks2; x1 += k0 + 2u;
  TFR(13) TFR(15) TFR(26) TFR(6)
  x0 += k0; x1 += k1 + 3u;
  TFR(17) TFR(29) TFR(16) TFR(24)
  x0 += k1; x1 += ks2 + 4u;
  TFR(13) TFR(15) TFR(26) TFR(6)
  x0 += ks2; x1 += k0 + 5u;
#undef TFR
  o0 = x0; o1 = x1;
}

// XLA ErfInv32 (Giles), exact coefficients
__device__ inline float erfinv32(float x){
  float w = -log1pf(-x*x);
  float p;
  if (w < 5.0f) {
    w = w - 2.5f;
    p = 2.81022636e-08f;
    p = fmaf(p, w, 3.43273939e-07f);
    p = fmaf(p, w, -3.5233877e-06f);
    p = fmaf(p, w, -4.39150654e-06f);
    p = fmaf(p, w, 0.00021858087f);
    p = fmaf(p, w, -0.00125372503f);
    p = fmaf(p, w, -0.00417768164f);
    p = fmaf(p, w, 0.246640727f);
    p = fmaf(p, w, 1.50140941f);
  } else {
    w = sqrtf(w) - 3.0f;
    p = -0.000200214257f;
    p = fmaf(p, w, 0.000100950558f);
    p = fmaf(p, w, 0.00134934322f);
    p = fmaf(p, w, -0.00367342844f);
    p = fmaf(p, w, 0.00573950773f);
    p = fmaf(p, w, -0.0076224613f);
    p = fmaf(p, w, 0.00943887047f);
    p = fmaf(p, w, 1.00167406f);
    p = fmaf(p, w, 2.83297682f);
  }
  return p * x;
}

__device__ inline void axisangle_R(float ax, float ay, float az, float R[9]){
  float th = sqrtf(ax*ax + ay*ay + az*az);
  float den = th + 1e-8f;
  float ux = ax/den, uy = ay/den, uz = az/den;
  float s = sinf(th), c = cosf(th);
  float omc = 1.0f - c;
  float xx=ux*ux, yy=uy*uy, zz=uz*uz;
  float xy=ux*uy, xz=ux*uz, yz=uy*uz;
  R[0] = 1.0f + omc*(-(yy+zz));
  R[1] = s*(-uz) + omc*xy;
  R[2] = s*uy    + omc*xz;
  R[3] = s*uz    + omc*xy;
  R[4] = 1.0f + omc*(-(xx+zz));
  R[5] = s*(-ux) + omc*yz;
  R[6] = s*(-uy) + omc*xz;
  R[7] = s*ux    + omc*yz;
  R[8] = 1.0f + omc*(-(xx+yy));
}

struct WArr { float w[MUU]; };

// ---------------- init (parity-0 state) ----------------
__global__ void k_init(float* mean, float* sigma, float* gbest_pos, float* gbest_fit){
  int i = blockIdx.x*blockDim.x + threadIdx.x;
  if (i < NB*6){
    mean[i] = 0.0f;
    gbest_pos[i] = 0.0f;
    int d = i % 6;
    sigma[i] = (d < 3) ? SIG0R : SIG0T;
  }
  if (i < NB) gbest_fit[i] = INFINITY;
}

// ---------------- permutation via exact radix-bucket ranking ----------------
// comp = key<<28 | pos<<14 | val (all fields unique per (key,pos)).
// Total order by comp == JAX's stable sort_key_val order.
// bucket B = comp>>52 == key>>24 (8 bits, 0..255).

__global__ void k_genc(uint64_t* comp, const int* __restrict__ payload,
                       uint32_t sa0, uint32_t sa1, uint32_t sb0, uint32_t sb1, int round){
  int i = blockIdx.x*blockDim.x + threadIdx.x;
  if (i >= 2*NPTS) return;
  int a = i >> 14;
  int idx = i & (NPTS-1);
  uint32_t kk0 = a ? sb0 : sa0;
  uint32_t kk1 = a ? sb1 : sa1;
  uint32_t o0,o1; tf2x32(kk0, kk1, 0u, (uint32_t)idx, o0, o1);
  uint32_t key = o0 ^ o1;   // partitionable 32-bit random bits
  uint64_t val = (round == 0) ? (uint64_t)idx : (uint64_t)payload[i];
  comp[i] = ((uint64_t)key << 28) | ((uint64_t)idx << 14) | val;
}

__global__ void k_hist(const uint64_t* __restrict__ comp, int* __restrict__ hist){
  int i = blockIdx.x*blockDim.x + threadIdx.x;
  if (i >= 2*NPTS) return;
  int a = i >> 14;
  int B = (int)(comp[i] >> 52);
  atomicAdd(&hist[a*256 + B], 1);
}

__global__ void k_scan(const int* __restrict__ hist, int* __restrict__ offs){
  int a = threadIdx.x;
  if (blockIdx.x != 0 || a >= 2) return;
  int s = 0;
  for (int b = 0; b < 256; ++b){ offs[a*256 + b] = s; s += hist[a*256 + b]; }
}

__global__ void k_bscat(const uint64_t* __restrict__ comp, const int* __restrict__ offs,
                        int* __restrict__ slot, uint64_t* __restrict__ grouped){
  int i = blockIdx.x*blockDim.x + threadIdx.x;
  if (i >= 2*NPTS) return;
  int a = i >> 14;
  uint64_t mc = comp[i];
  int B = (int)(mc >> 52);
  int p = offs[a*256 + B] + atomicAdd(&slot[a*256 + B], 1);
  grouped[(size_t)a*NPTS + p] = mc;
}

// exact rank = bucket offset + count of strictly-smaller elements in bucket
// (deterministic regardless of scatter order; comp values unique).
// Writes only ranks < limit, to outp[a*stride + r].
__global__ void k_rank(const uint64_t* __restrict__ grouped, const int* __restrict__ offs,
                       const int* __restrict__ hist, int* __restrict__ outp,
                       int stride, int limit){
  int i = blockIdx.x*blockDim.x + threadIdx.x;
  if (i >= 2*NPTS) return;
  int a = i >> 14;
  int p = i & (NPTS-1);
  uint64_t mc = grouped[(size_t)a*NPTS + p];
  int B = (int)(mc >> 52);
  int off = offs[a*256 + B];
  int sz  = hist[a*256 + B];
  int r = off;
  for (int q = off; q < off + sz; ++q)
    r += (grouped[(size_t)a*NPTS + q] < mc) ? 1 : 0;
  if (r < limit) outp[a*stride + r] = (int)(mc & 0x3FFFull);
}

__global__ void k_gather(const int* __restrict__ outS, const float* source, const float* target,
                         float* src_sub, float* tgt_sub){
  int t = blockIdx.x*blockDim.x + threadIdx.x;
  if (t >= 2*NB*SS) return;
  int a = t / (NB*SS);
  int r = t % (NB*SS);
  int b = r / SS;
  int s2 = r % SS;
  int val = outS[a*SS + s2];
  const float* inp = a ? target : source;
  float* outp = a ? tgt_sub : src_sub;
  for (int d = 0; d < 3; ++d)
    outp[((size_t)b*SS + s2)*3 + d] = inp[((size_t)b*NPTS + val)*3 + d];
}

// ---------------- fused iteration: redundant update-prologue + sample + eval ----------------
__global__ __launch_bounds__(256) void k_se(uint32_t ka, uint32_t kb, int it,
    float* __restrict__ mean_base, float* __restrict__ sigma_base,
    const float* __restrict__ src_sub, const float* __restrict__ tgt_sub,
    float* __restrict__ z_base, float* __restrict__ off_base,
    float* __restrict__ fit_base,
    float* __restrict__ gb_pos, float* __restrict__ gb_fit, WArr W){
  int c = blockIdx.x;
  int b = c / POPP;
  int tid = threadIdx.x;
  int wave = tid >> 6;
  int lane = tid & 63;

  int readP  = (it == 0) ? 0 : ((it-1)&1);
  int writeP = it & 1;
  const float* fitR = fit_base + readP*(NB*POPP);
  float*       fitW = fit_base + writeP*(NB*POPP);
  const float* zR   = z_base   + (size_t)readP*(NB*POPP*6);
  float*       zC   = z_base   + (size_t)writeP*(NB*POPP*6);
  const float* offR = off_base + (size_t)readP*(NB*POPP*6);
  float*       offC = off_base + (size_t)writeP*(NB*POPP*6);
  const float* sigR = sigma_base + readP*(NB*6);
  float*       sigW = sigma_base + writeP*(NB*6);
  const float* meanR = mean_base + readP*(NB*6);
  float*       meanW = mean_base + writeP*(NB*6);

  __shared__ float qmean[6], qsig[6];
  __shared__ float lfit[POPP];
  __shared__ int   order[POPP];
  __shared__ float mn[6], mzs[6];
  __shared__ float qoff[6];
  __shared__ float4 ysd[SS];
  __shared__ float4 xsd[SS];
  __shared__ float rmp[4][SS];
  __shared__ float cmp[4][SS];
  __shared__ float wpart[4];

  if (it > 0){
    if (tid < POPP) lfit[tid] = fitR[b*POPP + tid];
    __syncthreads();
    if (tid < POPP){
      float f = lfit[tid];
      int r = 0;
      for (int j = 0; j < POPP; ++j){
        float fj = lfit[j];
        r += (fj < f) || (fj == f && j < tid);   // stable ascending rank
      }
      order[r] = tid;
    }
    __syncthreads();
    if (tid < 6){
      float a = 0.0f, bz = 0.0f;
      for (int m = 0; m < MUU; ++m){
        int idx = order[m];
        a  = fmaf(W.w[m], offR[((size_t)b*POPP + idx)*6 + tid], a);
        bz = fmaf(W.w[m], zR [((size_t)b*POPP + idx)*6 + tid], bz);
      }
      mn[tid] = a; mzs[tid] = bz;
    }
    __syncthreads();
    if (tid == 0){
      float avg = (((((fabsf(mzs[0])+fabsf(mzs[1]))+fabsf(mzs[2]))+fabsf(mzs[3]))+fabsf(mzs[4]))+fabsf(mzs[5])) / 6.0f;
      float e = expf(0.3f * (avg - 1.0f));
      for (int d = 0; d < 6; ++d){
        float sN = sigR[b*6 + d] * e;
        float lo = (d < 3) ? SLOR : SLOT;
        float hi = (d < 3) ? SHIR : SHIT;
        sN = fminf(fmaxf(sN, lo), hi);
        qsig[d] = sN; sigW[b*6 + d] = sN;
        qmean[d] = mn[d]; meanW[b*6 + d] = mn[d];
      }
      int i0 = order[0];
      float bf = lfit[i0];
      if (bf < gb_fit[b]){
        gb_fit[b] = bf;
        for (int d = 0; d < 6; ++d) gb_pos[b*6 + d] = offR[((size_t)b*POPP + i0)*6 + d];
      }
    }
  } else {
    if (tid < 6){ qmean[tid] = meanR[b*6 + tid]; qsig[tid] = sigR[b*6 + tid]; }
  }
  __syncthreads();

  // ---- sampling (bitwise-identical trajectory) ----
  if (tid < 6){
    int i = c*6 + tid;
    uint32_t o0,o1; tf2x32(ka, kb, 0u, (uint32_t)i, o0, o1);
    uint32_t bits = o0 ^ o1;
    float u = __uint_as_float((bits >> 9) | 0x3F800000u) - 1.0f;
    u = u * 2.0f + ULOW;
    u = fmaxf(ULOW, u);
    float zz = SQRT2F * erfinv32(u);
    float m = qmean[tid], sg = qsig[tid];
    float v = fmaf(sg, zz, m);
    float lim = (tid < 3) ? ROTF : 1.0f;
    v = fminf(fmaxf(v, -lim), lim);
    zC[i] = zz; offC[i] = v; qoff[tid] = v;
  }
  __syncthreads();

  float R[9];
  axisangle_R(qoff[0], qoff[1], qoff[2], R);
  float tx=qoff[3], ty=qoff[4], tz=qoff[5];

  {
    const float* tp = tgt_sub + ((size_t)b*SS + tid)*3;
    float Y0=tp[0], Y1=tp[1], Y2=tp[2];
    float sy = fmaf(Y2,Y2, fmaf(Y1,Y1, Y0*Y0));
    ysd[tid] = make_float4(-2.0f*Y0, -2.0f*Y1, -2.0f*Y2, sy);
  }
  {
    const float* sp = src_sub + ((size_t)b*SS + tid)*3;
    float X0=sp[0], X1=sp[1], X2=sp[2];
    float px = fmaf(X2, R[2], fmaf(X1, R[1], X0*R[0])) + tx;
    float py = fmaf(X2, R[5], fmaf(X1, R[4], X0*R[3])) + ty;
    float pz = fmaf(X2, R[8], fmaf(X1, R[7], X0*R[6])) + tz;
    float sx = fmaf(pz,pz, fmaf(py,py, px*px));
    xsd[tid] = make_float4(-2.0f*px, -2.0f*py, -2.0f*pz, sx);
  }
  __syncthreads();

  float pxj[4],pyj[4],pzj[4];
  float yxj[4],yyj[4],yzj[4];
  #pragma unroll
  for (int j = 0; j < 4; ++j){
    int i = lane + 64*j;
    float4 xv = xsd[i];
    pxj[j] = -0.5f*xv.x; pyj[j] = -0.5f*xv.y; pzj[j] = -0.5f*xv.z;
    float4 yv = ysd[i];
    yxj[j] = -0.5f*yv.x; yyj[j] = -0.5f*yv.y; yzj[j] = -0.5f*yv.z;
  }

  float rm0=INFINITY, rm1=INFINITY, rm2=INFINITY, rm3=INFINITY;
  float cm0=INFINITY, cm1=INFINITY, cm2=INFINITY, cm3=INFINITY;
  int tbeg = wave*64;
  #pragma unroll 8
  for (int t = tbeg; t < tbeg+64; ++t){
    float4 yv = ysd[t];
    float4 xv = xsd[t];
    rm0 = fminf(rm0, fmaf(pxj[0], yv.x, fmaf(pyj[0], yv.y, fmaf(pzj[0], yv.z, yv.w))));
    rm1 = fminf(rm1, fmaf(pxj[1], yv.x, fmaf(pyj[1], yv.y, fmaf(pzj[1], yv.z, yv.w))));
    rm2 = fminf(rm2, fmaf(pxj[2], yv.x, fmaf(pyj[2], yv.y, fmaf(pzj[2], yv.z, yv.w))));
    rm3 = fminf(rm3, fmaf(pxj[3], yv.x, fmaf(pyj[3], yv.y, fmaf(pzj[3], yv.z, yv.w))));
    cm0 = fminf(cm0, fmaf(yxj[0], xv.x, fmaf(yyj[0], xv.y, fmaf(yzj[0], xv.z, xv.w))));
    cm1 = fminf(cm1, fmaf(yxj[1], xv.x, fmaf(yyj[1], xv.y, fmaf(yzj[1], xv.z, xv.w))));
    cm2 = fminf(cm2, fmaf(yxj[2], xv.x, fmaf(yyj[2], xv.y, fmaf(yzj[2], xv.z, xv.w))));
    cm3 = fminf(cm3, fmaf(yxj[3], xv.x, fmaf(yyj[3], xv.y, fmaf(yzj[3], xv.z, xv.w))));
  }

  rmp[wave][lane+  0] = rm0;  cmp[wave][lane+  0] = cm0;
  rmp[wave][lane+ 64] = rm1;  cmp[wave][lane+ 64] = cm1;
  rmp[wave][lane+128] = rm2;  cmp[wave][lane+128] = cm2;
  rmp[wave][lane+192] = rm3;  cmp[wave][lane+192] = cm3;
  __syncthreads();

  float fx = xsd[tid].w + fminf(fminf(rmp[0][tid], rmp[1][tid]),
                                fminf(rmp[2][tid], rmp[3][tid]));
  float fy = ysd[tid].w + fminf(fminf(cmp[0][tid], cmp[1][tid]),
                                fminf(cmp[2][tid], cmp[3][tid]));
  float acc = fx + fy;

  for (int m = 32; m > 0; m >>= 1) acc += __shfl_xor(acc, m, 64);
  if (lane == 0) wpart[wave] = acc;
  __syncthreads();
  if (tid == 0) fitW[c] = (((wpart[0]+wpart[1])+wpart[2])+wpart[3]) * (1.0f/256.0f);
}

// ---------------- chamfer fitness for the final mean ----------------
__global__ __launch_bounds__(128) void k_eval(const float* __restrict__ pos, int Pn,
    const float* __restrict__ src_sub, const float* __restrict__ tgt_sub,
    float* __restrict__ fit){
  int c = blockIdx.x;
  int b = c / Pn;
  int tid = threadIdx.x;
  int wave = tid >> 6;
  int lane = tid & 63;
  __shared__ float4 ysd[SS];
  __shared__ float4 xsd[SS];
  __shared__ float wpart[2];

  const float* q = pos + (size_t)c*6;
  float R[9];
  axisangle_R(q[0], q[1], q[2], R);
  float tx=q[3], ty=q[4], tz=q[5];

  for (int i = tid; i < SS; i += 128){
    const float* tp = tgt_sub + ((size_t)b*SS + i)*3;
    float Y0=tp[0], Y1=tp[1], Y2=tp[2];
    float sy = fmaf(Y2,Y2, fmaf(Y1,Y1, Y0*Y0));
    ysd[i] = make_float4(-2.0f*Y0, -2.0f*Y1, -2.0f*Y2, sy);
  }

  int xi0 = wave*128 + lane;
  int xi1 = xi0 + 64;
  float px0,py0,pz0,sx0, px1,py1,pz1,sx1;
  {
    const float* sp = src_sub + ((size_t)b*SS + xi0)*3;
    float X0=sp[0], X1=sp[1], X2=sp[2];
    px0 = fmaf(X2, R[2], fmaf(X1, R[1], X0*R[0])) + tx;
    py0 = fmaf(X2, R[5], fmaf(X1, R[4], X0*R[3])) + ty;
    pz0 = fmaf(X2, R[8], fmaf(X1, R[7], X0*R[6])) + tz;
    sx0 = fmaf(pz0,pz0, fmaf(py0,py0, px0*px0));
    xsd[xi0] = make_float4(-2.0f*px0, -2.0f*py0, -2.0f*pz0, sx0);
  }
  {
    const float* sp = src_sub + ((size_t)b*SS + xi1)*3;
    float X0=sp[0], X1=sp[1], X2=sp[2];
    px1 = fmaf(X2, R[2], fmaf(X1, R[1], X0*R[0])) + tx;
    py1 = fmaf(X2, R[5], fmaf(X1, R[4], X0*R[3])) + ty;
    pz1 = fmaf(X2, R[8], fmaf(X1, R[7], X0*R[6])) + tz;
    sx1 = fmaf(pz1,pz1, fmaf(py1,py1, px1*px1));
    xsd[xi1] = make_float4(-2.0f*px1, -2.0f*py1, -2.0f*pz1, sx1);
  }
  __syncthreads();

  float rm0 = INFINITY, rm1 = INFINITY;
  #pragma unroll 8
  for (int t = 0; t < SS; ++t){
    float4 yv = ysd[t];
    rm0 = fminf(rm0, fmaf(px0, yv.x, fmaf(py0, yv.y, fmaf(pz0, yv.z, yv.w))));
    rm1 = fminf(rm1, fmaf(px1, yv.x, fmaf(py1, yv.y, fmaf(pz1, yv.z, yv.w))));
  }
  float acc = (sx0 + rm0) + (sx1 + rm1);

  float4 yv0 = ysd[xi0];
  float4 yv1 = ysd[xi1];
  float yx0 = -0.5f*yv0.x, yy0 = -0.5f*yv0.y, yz0 = -0.5f*yv0.z, sy0 = yv0.w;
  float yx1 = -0.5f*yv1.x, yy1 = -0.5f*yv1.y, yz1 = -0.5f*yv1.z, sy1 = yv1.w;
  float cm0 = INFINITY, cm1 = INFINITY;
  #pragma unroll 8
  for (int t = 0; t < SS; ++t){
    float4 xv = xsd[t];
    cm0 = fminf(cm0, fmaf(yx0, xv.x, fmaf(yy0, xv.y, fmaf(yz0, xv.z, xv.w))));
    cm1 = fminf(cm1, fmaf(yx1, xv.x, fmaf(yy1, xv.y, fmaf(yz1, xv.z, xv.w))));
  }
  acc += (sy0 + cm0) + (sy1 + cm1);

  for (int m = 32; m > 0; m >>= 1) acc += __shfl_xor(acc, m, 64);
  if (lane == 0) wpart[wave] = acc;
  __syncthreads();
  if (tid == 0) fit[c] = (wpart[0] + wpart[1]) * (1.0f/256.0f);
}

// ---------------- selection + update (final iteration only) ----------------
__global__ __launch_bounds__(64) void k_update(const float* __restrict__ fit,
    const float* __restrict__ off, const float* __restrict__ z,
    float* mean, float* sigma, float* gbest_pos, float* gbest_fit, WArr W){
  int b = blockIdx.x;
  int tid = threadIdx.x;
  __shared__ float lfit[POPP];
  __shared__ int order[POPP];
  __shared__ float mn[6], mz[6];
  if (tid < POPP) lfit[tid] = fit[b*POPP + tid];
  __syncthreads();
  if (tid < POPP){
    float f = lfit[tid];
    int r = 0;
    for (int j = 0; j < POPP; ++j){
      float fj = lfit[j];
      r += (fj < f) || (fj == f && j < tid);   // stable ascending rank
    }
    order[r] = tid;
  }
  __syncthreads();
  if (tid < 6){
    float a = 0.0f, bz = 0.0f;
    for (int m = 0; m < MUU; ++m){
      int idx = order[m];
      a  = fmaf(W.w[m], off[((size_t)b*POPP + idx)*6 + tid], a);
      bz = fmaf(W.w[m], z  [((size_t)b*POPP + idx)*6 + tid], bz);
    }
    mn[tid] = a; mz[tid] = bz;
  }
  __syncthreads();
  if (tid == 0){
    float avg = (((((fabsf(mz[0])+fabsf(mz[1]))+fabsf(mz[2]))+fabsf(mz[3]))+fabsf(mz[4]))+fabsf(mz[5])) / 6.0f;
    float e = expf(0.3f * (avg - 1.0f));
    for (int d = 0; d < 6; ++d){
      float sN = sigma[b*6 + d] * e;
      float lo = (d < 3) ? SLOR : SLOT;
      float hi = (d < 3) ? SHIR : SHIT;
      sN = fminf(fmaxf(sN, lo), hi);
      sigma[b*6 + d] = sN;
      mean[b*6 + d] = mn[d];
    }
    int i0 = order[0];
    float bf = lfit[i0];
    if (bf < gbest_fit[b]){
      gbest_fit[b] = bf;
      for (int d = 0; d < 6; ++d) gbest_pos[b*6 + d] = off[((size_t)b*POPP + i0)*6 + d];
    }
  }
}

// ---------------- finalize: choose gbest vs mean, emit R,t ----------------
__global__ void k_finalize(const float* mean, const float* mean_fit,
                           const float* gbest_pos, const float* gbest_fit, float* out){
  int b = blockIdx.x;
  if (threadIdx.x != 0) return;
  bool um = mean_fit[b] < gbest_fit[b];
  float g[6];
  for (int d = 0; d < 6; ++d) g[d] = um ? mean[b*6 + d] : gbest_pos[b*6 + d];
  float R[9];
  axisangle_R(g[0], g[1], g[2], R);
  for (int i = 0; i < 9; ++i) out[b*9 + i] = R[i];
  for (int d = 0; d < 3; ++d) out[NB*9 + b*3 + d] = g[3 + d];
}

__global__ void k_aligned(const float* __restrict__ src, const float* __restrict__ out_rt,
                          float* __restrict__ aligned){
  int idx = blockIdx.x*blockDim.x + threadIdx.x;
  if (idx >= NB*NPTS) return;
  int b = idx / NPTS;
  const float* R = out_rt + b*9;
  const float* t = out_rt + NB*9 + b*3;
  const float* p = src + (size_t)idx*3;
  float X0=p[0], X1=p[1], X2=p[2];
  float* o = aligned + (size_t)idx*3;
  o[0] = fmaf(X2, R[2], fmaf(X1, R[1], X0*R[0])) + t[0];
  o[1] = fmaf(X2, R[5], fmaf(X1, R[4], X0*R[3])) + t[1];
  o[2] = fmaf(X2, R[8], fmaf(X1, R[7], X0*R[6])) + t[2];
}

// ---------------- host ----------------
struct HKey { uint32_t a, b; };
static inline HKey h_tf(HKey k, uint32_t x0, uint32_t x1){
  uint32_t o0,o1; tf2x32(k.a, k.b, x0, x1, o0, o1);
  return {o0, o1};
}

extern "C" void kernel_launch(void* const* d_in, const int* in_sizes, int n_in,
                              void* d_out, int out_size, void* d_ws, size_t ws_size,
                              hipStream_t stream){
  const float* source = (const float*)d_in[0];
  const float* target = (const float*)d_in[1];
  float* out = (float*)d_out;

  // ---- workspace layout (256B aligned chunks; parity-doubled state buffers) ----
  uint8_t* w = (uint8_t*)d_ws;
  size_t o = 0;
  auto alloc = [&](size_t bytes){ void* p = w + o; o += (bytes + 255) & ~(size_t)255; return p; };
  uint64_t* comp    = (uint64_t*)alloc(2*(size_t)NPTS*8);
  uint64_t* grouped = (uint64_t*)alloc(2*(size_t)NPTS*8);
  int* perm1 = (int*)alloc(2*(size_t)NPTS*4);
  int* outS  = (int*)alloc(2*(size_t)SS*4);
  int* hs    = (int*)alloc(6*512*4);   // hist1|slot1|hist2|slot2|offs1|offs2 (512 ints each)
  float* src_sub   = (float*)alloc((size_t)NB*SS*3*4);
  float* tgt_sub   = (float*)alloc((size_t)NB*SS*3*4);
  float* z_buf     = (float*)alloc(2*(size_t)NB*POPP*6*4);
  float* off_buf   = (float*)alloc(2*(size_t)NB*POPP*6*4);
  float* fit_buf   = (float*)alloc(2*(size_t)NB*POPP*4);
  float* mean_buf  = (float*)alloc(2*(size_t)NB*6*4);
  float* sigma_buf = (float*)alloc(2*(size_t)NB*6*4);
  float* gb_pos    = (float*)alloc((size_t)NB*6*4);
  float* gb_fit    = (float*)alloc((size_t)NB*4);
  float* mean_fit  = (float*)alloc((size_t)NB*4);
  (void)ws_size; (void)in_sizes; (void)n_in; (void)out_size;

  int* hist1 = hs + 0*512;
  int* slot1 = hs + 1*512;
  int* hist2 = hs + 2*512;
  int* slot2 = hs + 3*512;
  int* offs1 = hs + 4*512;
  int* offs2 = hs + 5*512;

  // ---- host-side JAX key derivation (threefry, partitionable mode) ----
  HKey key0 = {0u, 42u};
  HKey k1 = h_tf(key0, 0u, 0u);
  HKey k2 = h_tf(key0, 0u, 1u);
  HKey k3 = h_tf(key0, 0u, 2u);
  HKey srcA  = h_tf(k1, 0u, 0u);
  HKey srcS1 = h_tf(k1, 0u, 1u);
  HKey srcS2 = h_tf(srcA, 0u, 1u);
  HKey tgtA  = h_tf(k2, 0u, 0u);
  HKey tgtS1 = h_tf(k2, 0u, 1u);
  HKey tgtS2 = h_tf(tgtA, 0u, 1u);
  HKey itk[NITERS];
  for (int j = 0; j < NITERS; ++j) itk[j] = h_tf(k3, 0u, (uint32_t)j);

  // ---- recombination weights (numpy double math, cast f32) ----
  WArr W;
  {
    double lw[MUU], s = 0.0;
    for (int m = 0; m < MUU; ++m){ lw[m] = log((double)MUU + 0.5) - log((double)(m+1)); s += lw[m]; }
    for (int m = 0; m < MUU; ++m) W.w[m] = (float)(lw[m] / s);
  }

  // zero hist/slot for both rounds (re-done every call -> deterministic)
  hipMemsetAsync(hs, 0, 4*512*4, stream);
  hipLaunchKernelGGL(k_init, dim3(1), dim3(256), 0, stream, mean_buf, sigma_buf, gb_pos, gb_fit);

  // ---- permutation round 1: rank by (key1, pos), payload = pos -> perm1 (full) ----
  hipLaunchKernelGGL(k_genc,  dim3(128), dim3(256), 0, stream,
                     comp, (const int*)nullptr, srcS1.a, srcS1.b, tgtS1.a, tgtS1.b, 0);
  hipLaunchKernelGGL(k_hist,  dim3(128), dim3(256), 0, stream, comp, hist1);
  hipLaunchKernelGGL(k_scan,  dim3(1),   dim3(64),  0, stream, hist1, offs1);
  hipLaunchKernelGGL(k_bscat, dim3(128), dim3(256), 0, stream, comp, offs1, slot1, grouped);
  hipLaunchKernelGGL(k_rank,  dim3(128), dim3(256), 0, stream, grouped, offs1, hist1, perm1, NPTS, NPTS);

  // ---- permutation round 2: rank by (key2, pos), payload = perm1 -> outS (first SS) ----
  hipLaunchKernelGGL(k_genc,  dim3(128), dim3(256), 0, stream,
                     comp, perm1, srcS2.a, srcS2.b, tgtS2.a, tgtS2.b, 1);
  hipLaunchKernelGGL(k_hist,  dim3(128), dim3(256), 0, stream, comp, hist2);
  hipLaunchKernelGGL(k_scan,  dim3(1),   dim3(64),  0, stream, hist2, offs2);
  hipLaunchKernelGGL(k_bscat, dim3(128), dim3(256), 0, stream, comp, offs2, slot2, grouped);
  hipLaunchKernelGGL(k_rank,  dim3(128), dim3(256), 0, stream, grouped, offs2, hist2, outS, SS, SS);

  hipLaunchKernelGGL(k_gather, dim3(64), dim3(256), 0, stream,
                     outS, source, target, src_sub, tgt_sub);

  // ---- CMA-ES main loop: ONE kernel per iteration (update fused as prologue) ----
  for (int it = 0; it < NITERS; ++it){
    hipLaunchKernelGGL(k_se, dim3(NB*POPP), dim3(256), 0, stream,
                       itk[it].a, itk[it].b, it, mean_buf, sigma_buf,
                       src_sub, tgt_sub, z_buf, off_buf, fit_buf,
                       gb_pos, gb_fit, W);
  }

  // ---- final (iteration-30) update on parity-1 state ----
  hipLaunchKernelGGL(k_update, dim3(NB), dim3(64), 0, stream,
                     fit_buf + NB*POPP, off_buf + (size_t)NB*POPP*6, z_buf + (size_t)NB*POPP*6,
                     mean_buf + NB*6, sigma_buf + NB*6, gb_pos, gb_fit, W);

  // ---- final mean evaluation + output ----
  hipLaunchKernelGGL(k_eval, dim3(NB), dim3(128), 0, stream,
                     mean_buf + NB*6, 1, src_sub, tgt_sub, mean_fit);
  hipLaunchKernelGGL(k_finalize, dim3(NB), dim3(64), 0, stream,
                     mean_buf + NB*6, mean_fit, gb_pos, gb_fit, out);
  hipLaunchKernelGGL(k_aligned, dim3((NB*NPTS + 255)/256), dim3(256), 0, stream,
                     source, out, out + NB*9 + NB*3);
}

// Round 22
// 841.014 us; speedup vs baseline: 1.2098x; 1.0045x over previous
//
#include <hip/hip_runtime.h>
#include <stdint.h>
#include <math.h>

#define NB 32
#define NPTS 16384
#define SS 256
#define POPP 50
#define MUU 25
#define NITERS 30

#define ROTF  ((float)0.7853981633974483)
#define SIG0R ((float)(0.7853981633974483*0.3))
#define SIG0T ((float)0.3)
#define SLOR  ((float)(0.7853981633974483*0.01))
#define SHIR  ((float)(0.7853981633974483*0.5))
#define SLOT  ((float)0.01)
#define SHIT  ((float)0.5)
#define SQRT2F ((float)1.4142135623730951)
#define ULOW  (-0.99999994f)

// ---------------- threefry2x32 (JAX-exact) ----------------
__host__ __device__ inline uint32_t rotl32(uint32_t v, int n){ return (v<<n)|(v>>(32-n)); }

__host__ __device__ inline void tf2x32(uint32_t k0, uint32_t k1, uint32_t x0, uint32_t x1,
                                       uint32_t &o0, uint32_t &o1){
  uint32_t ks2 = k0 ^ k1 ^ 0x1BD11BDAu;
  x0 += k0; x1 += k1;
#define TFR(r) { x0 += x1; x1 = rotl32(x1, r); x1 ^= x0; }
  TFR(13) TFR(15) TFR(26) TFR(6)
  x0 += k1; x1 += ks2 + 1u;
  TFR(17) TFR(29) TFR(16) TFR(24)
  x0 += ks2; x1 += k0 + 2u;
  TFR(13) TFR(15) TFR(26) TFR(6)
  x0 += k0; x1 += k1 + 3u;
  TFR(17) TFR(29) TFR(16) TFR(24)
  x0 += k1; x1 += ks2 + 4u;
  TFR(13) TFR(15) TFR(26) TFR(6)
  x0 += ks2; x1 += k0 + 5u;
#undef TFR
  o0 = x0; o1 = x1;
}

// XLA ErfInv32 (Giles), exact coefficients
__device__ inline float erfinv32(float x){
  float w = -log1pf(-x*x);
  float p;
  if (w < 5.0f) {
    w = w - 2.5f;
    p = 2.81022636e-08f;
    p = fmaf(p, w, 3.43273939e-07f);
    p = fmaf(p, w, -3.5233877e-06f);
    p = fmaf(p, w, -4.39150654e-06f);
    p = fmaf(p, w, 0.00021858087f);
    p = fmaf(p, w, -0.00125372503f);
    p = fmaf(p, w, -0.00417768164f);
    p = fmaf(p, w, 0.246640727f);
    p = fmaf(p, w, 1.50140941f);
  } else {
    w = sqrtf(w) - 3.0f;
    p = -0.000200214257f;
    p = fmaf(p, w, 0.000100950558f);
    p = fmaf(p, w, 0.00134934322f);
    p = fmaf(p, w, -0.00367342844f);
    p = fmaf(p, w, 0.00573950773f);
    p = fmaf(p, w, -0.0076224613f);
    p = fmaf(p, w, 0.00943887047f);
    p = fmaf(p, w, 1.00167406f);
    p = fmaf(p, w, 2.83297682f);
  }
  return p * x;
}

__device__ inline void axisangle_R(float ax, float ay, float az, float R[9]){
  float th = sqrtf(ax*ax + ay*ay + az*az);
  float den = th + 1e-8f;
  float ux = ax/den, uy = ay/den, uz = az/den;
  float s = sinf(th), c = cosf(th);
  float omc = 1.0f - c;
  float xx=ux*ux, yy=uy*uy, zz=uz*uz;
  float xy=ux*uy, xz=ux*uz, yz=uy*uz;
  R[0] = 1.0f + omc*(-(yy+zz));
  R[1] = s*(-uz) + omc*xy;
  R[2] = s*uy    + omc*xz;
  R[3] = s*uz    + omc*xy;
  R[4] = 1.0f + omc*(-(xx+zz));
  R[5] = s*(-ux) + omc*yz;
  R[6] = s*(-uy) + omc*xz;
  R[7] = s*ux    + omc*yz;
  R[8] = 1.0f + omc*(-(xx+yy));
}

struct WArr { float w[MUU]; };

// ---------------- init (parity-0 state) ----------------
__global__ void k_init(float* mean, float* sigma, float* gbest_pos, float* gbest_fit){
  int i = blockIdx.x*blockDim.x + threadIdx.x;
  if (i < NB*6){
    mean[i] = 0.0f;
    gbest_pos[i] = 0.0f;
    int d = i % 6;
    sigma[i] = (d < 3) ? SIG0R : SIG0T;
  }
  if (i < NB) gbest_fit[i] = INFINITY;
}

// ---------------- permutation via exact radix-bucket ranking ----------------
// comp = key<<28 | pos<<14 | val (all fields unique per (key,pos)).
// Total order by comp == JAX's stable sort_key_val order.
// bucket B = comp>>52 == key>>24 (8 bits, 0..255).

__global__ void k_genc(uint64_t* comp, const int* __restrict__ payload,
                       uint32_t sa0, uint32_t sa1, uint32_t sb0, uint32_t sb1, int round){
  int i = blockIdx.x*blockDim.x + threadIdx.x;
  if (i >= 2*NPTS) return;
  int a = i >> 14;
  int idx = i & (NPTS-1);
  uint32_t kk0 = a ? sb0 : sa0;
  uint32_t kk1 = a ? sb1 : sa1;
  uint32_t o0,o1; tf2x32(kk0, kk1, 0u, (uint32_t)idx, o0, o1);
  uint32_t key = o0 ^ o1;   // partitionable 32-bit random bits
  uint64_t val = (round == 0) ? (uint64_t)idx : (uint64_t)payload[i];
  comp[i] = ((uint64_t)key << 28) | ((uint64_t)idx << 14) | val;
}

__global__ void k_hist(const uint64_t* __restrict__ comp, int* __restrict__ hist){
  int i = blockIdx.x*blockDim.x + threadIdx.x;
  if (i >= 2*NPTS) return;
  int a = i >> 14;
  int B = (int)(comp[i] >> 52);
  atomicAdd(&hist[a*256 + B], 1);
}

__global__ void k_scan(const int* __restrict__ hist, int* __restrict__ offs){
  int a = threadIdx.x;
  if (blockIdx.x != 0 || a >= 2) return;
  int s = 0;
  for (int b = 0; b < 256; ++b){ offs[a*256 + b] = s; s += hist[a*256 + b]; }
}

__global__ void k_bscat(const uint64_t* __restrict__ comp, const int* __restrict__ offs,
                        int* __restrict__ slot, uint64_t* __restrict__ grouped){
  int i = blockIdx.x*blockDim.x + threadIdx.x;
  if (i >= 2*NPTS) return;
  int a = i >> 14;
  uint64_t mc = comp[i];
  int B = (int)(mc >> 52);
  int p = offs[a*256 + B] + atomicAdd(&slot[a*256 + B], 1);
  grouped[(size_t)a*NPTS + p] = mc;
}

// exact rank = bucket offset + count of strictly-smaller elements in bucket
// (deterministic regardless of scatter order; comp values unique).
__global__ void k_rank(const uint64_t* __restrict__ grouped, const int* __restrict__ offs,
                       const int* __restrict__ hist, int* __restrict__ outp,
                       int stride, int limit){
  int i = blockIdx.x*blockDim.x + threadIdx.x;
  if (i >= 2*NPTS) return;
  int a = i >> 14;
  int p = i & (NPTS-1);
  uint64_t mc = grouped[(size_t)a*NPTS + p];
  int B = (int)(mc >> 52);
  int off = offs[a*256 + B];
  int sz  = hist[a*256 + B];
  int r = off;
  for (int q = off; q < off + sz; ++q)
    r += (grouped[(size_t)a*NPTS + q] < mc) ? 1 : 0;
  if (r < limit) outp[a*stride + r] = (int)(mc & 0x3FFFull);
}

__global__ void k_gather(const int* __restrict__ outS, const float* source, const float* target,
                         float* src_sub, float* tgt_sub){
  int t = blockIdx.x*blockDim.x + threadIdx.x;
  if (t >= 2*NB*SS) return;
  int a = t / (NB*SS);
  int r = t % (NB*SS);
  int b = r / SS;
  int s2 = r % SS;
  int val = outS[a*SS + s2];
  const float* inp = a ? target : source;
  float* outp = a ? tgt_sub : src_sub;
  for (int d = 0; d < 3; ++d)
    outp[((size_t)b*SS + s2)*3 + d] = inp[((size_t)b*NPTS + val)*3 + d];
}

// ---------------- fused iteration: redundant update-prologue + sample + eval ----------------
__global__ __launch_bounds__(256) void k_se(uint32_t ka, uint32_t kb, int it,
    float* __restrict__ mean_base, float* __restrict__ sigma_base,
    const float* __restrict__ src_sub, const float* __restrict__ tgt_sub,
    float* __restrict__ z_base, float* __restrict__ off_base,
    float* __restrict__ fit_base,
    float* __restrict__ gb_pos, float* __restrict__ gb_fit, WArr W){
  int c = blockIdx.x;
  int b = c / POPP;
  int tid = threadIdx.x;
  int wave = tid >> 6;
  int lane = tid & 63;

  int readP  = (it == 0) ? 0 : ((it-1)&1);
  int writeP = it & 1;
  const float* fitR = fit_base + readP*(NB*POPP);
  float*       fitW = fit_base + writeP*(NB*POPP);
  const float* zR   = z_base   + (size_t)readP*(NB*POPP*6);
  float*       zC   = z_base   + (size_t)writeP*(NB*POPP*6);
  const float* offR = off_base + (size_t)readP*(NB*POPP*6);
  float*       offC = off_base + (size_t)writeP*(NB*POPP*6);
  const float* sigR = sigma_base + readP*(NB*6);
  float*       sigW = sigma_base + writeP*(NB*6);
  const float* meanR = mean_base + readP*(NB*6);
  float*       meanW = mean_base + writeP*(NB*6);

  __shared__ float qmean[6], qsig[6];
  __shared__ float lfit[POPP];
  __shared__ int   order[POPP];
  __shared__ float mn[6], mzs[6];
  __shared__ float qoff[6];
  __shared__ float4 ysd[SS];
  __shared__ float4 xsd[SS];
  __shared__ float rmp[4][SS];
  __shared__ float cmp[4][SS];
  __shared__ float wpart[4];

  if (it > 0){
    if (tid < POPP) lfit[tid] = fitR[b*POPP + tid];
    __syncthreads();
    if (tid < POPP){
      float f = lfit[tid];
      int r = 0;
      for (int j = 0; j < POPP; ++j){
        float fj = lfit[j];
        r += (fj < f) || (fj == f && j < tid);   // stable ascending rank
      }
      order[r] = tid;
    }
    __syncthreads();
    if (tid < 6){
      float a = 0.0f, bz = 0.0f;
      for (int m = 0; m < MUU; ++m){
        int idx = order[m];
        a  = fmaf(W.w[m], offR[((size_t)b*POPP + idx)*6 + tid], a);
        bz = fmaf(W.w[m], zR [((size_t)b*POPP + idx)*6 + tid], bz);
      }
      mn[tid] = a; mzs[tid] = bz;
    }
    __syncthreads();
    if (tid == 0){
      float avg = (((((fabsf(mzs[0])+fabsf(mzs[1]))+fabsf(mzs[2]))+fabsf(mzs[3]))+fabsf(mzs[4]))+fabsf(mzs[5])) / 6.0f;
      float e = expf(0.3f * (avg - 1.0f));
      for (int d = 0; d < 6; ++d){
        float sN = sigR[b*6 + d] * e;
        float lo = (d < 3) ? SLOR : SLOT;
        float hi = (d < 3) ? SHIR : SHIT;
        sN = fminf(fmaxf(sN, lo), hi);
        qsig[d] = sN; sigW[b*6 + d] = sN;
        qmean[d] = mn[d]; meanW[b*6 + d] = mn[d];
      }
      int i0 = order[0];
      float bf = lfit[i0];
      if (bf < gb_fit[b]){
        gb_fit[b] = bf;
        for (int d = 0; d < 6; ++d) gb_pos[b*6 + d] = offR[((size_t)b*POPP + i0)*6 + d];
      }
    }
  } else {
    if (tid < 6){ qmean[tid] = meanR[b*6 + tid]; qsig[tid] = sigR[b*6 + tid]; }
  }
  __syncthreads();

  // ---- sampling (bitwise-identical trajectory) ----
  if (tid < 6){
    int i = c*6 + tid;
    uint32_t o0,o1; tf2x32(ka, kb, 0u, (uint32_t)i, o0, o1);
    uint32_t bits = o0 ^ o1;
    float u = __uint_as_float((bits >> 9) | 0x3F800000u) - 1.0f;
    u = u * 2.0f + ULOW;
    u = fmaxf(ULOW, u);
    float zz = SQRT2F * erfinv32(u);
    float m = qmean[tid], sg = qsig[tid];
    float v = fmaf(sg, zz, m);
    float lim = (tid < 3) ? ROTF : 1.0f;
    v = fminf(fmaxf(v, -lim), lim);
    zC[i] = zz; offC[i] = v; qoff[tid] = v;
  }
  __syncthreads();

  float R[9];
  axisangle_R(qoff[0], qoff[1], qoff[2], R);
  float tx=qoff[3], ty=qoff[4], tz=qoff[5];

  {
    const float* tp = tgt_sub + ((size_t)b*SS + tid)*3;
    float Y0=tp[0], Y1=tp[1], Y2=tp[2];
    float sy = fmaf(Y2,Y2, fmaf(Y1,Y1, Y0*Y0));
    ysd[tid] = make_float4(-2.0f*Y0, -2.0f*Y1, -2.0f*Y2, sy);
  }
  {
    const float* sp = src_sub + ((size_t)b*SS + tid)*3;
    float X0=sp[0], X1=sp[1], X2=sp[2];
    float px = fmaf(X2, R[2], fmaf(X1, R[1], X0*R[0])) + tx;
    float py = fmaf(X2, R[5], fmaf(X1, R[4], X0*R[3])) + ty;
    float pz = fmaf(X2, R[8], fmaf(X1, R[7], X0*R[6])) + tz;
    float sx = fmaf(pz,pz, fmaf(py,py, px*px));
    xsd[tid] = make_float4(-2.0f*px, -2.0f*py, -2.0f*pz, sx);
  }
  __syncthreads();

  float pxj[4],pyj[4],pzj[4];
  float yxj[4],yyj[4],yzj[4];
  #pragma unroll
  for (int j = 0; j < 4; ++j){
    int i = lane + 64*j;
    float4 xv = xsd[i];
    pxj[j] = -0.5f*xv.x; pyj[j] = -0.5f*xv.y; pzj[j] = -0.5f*xv.z;
    float4 yv = ysd[i];
    yxj[j] = -0.5f*yv.x; yyj[j] = -0.5f*yv.y; yzj[j] = -0.5f*yv.z;
  }

  float rm0=INFINITY, rm1=INFINITY, rm2=INFINITY, rm3=INFINITY;
  float cm0=INFINITY, cm1=INFINITY, cm2=INFINITY, cm3=INFINITY;
  int tbeg = wave*64;
  #pragma unroll 8
  for (int t = tbeg; t < tbeg+64; ++t){
    float4 yv = ysd[t];
    float4 xv = xsd[t];
    rm0 = fminf(rm0, fmaf(pxj[0], yv.x, fmaf(pyj[0], yv.y, fmaf(pzj[0], yv.z, yv.w))));
    rm1 = fminf(rm1, fmaf(pxj[1], yv.x, fmaf(pyj[1], yv.y, fmaf(pzj[1], yv.z, yv.w))));
    rm2 = fminf(rm2, fmaf(pxj[2], yv.x, fmaf(pyj[2], yv.y, fmaf(pzj[2], yv.z, yv.w))));
    rm3 = fminf(rm3, fmaf(pxj[3], yv.x, fmaf(pyj[3], yv.y, fmaf(pzj[3], yv.z, yv.w))));
    cm0 = fminf(cm0, fmaf(yxj[0], xv.x, fmaf(yyj[0], xv.y, fmaf(yzj[0], xv.z, xv.w))));
    cm1 = fminf(cm1, fmaf(yxj[1], xv.x, fmaf(yyj[1], xv.y, fmaf(yzj[1], xv.z, xv.w))));
    cm2 = fminf(cm2, fmaf(yxj[2], xv.x, fmaf(yyj[2], xv.y, fmaf(yzj[2], xv.z, xv.w))));
    cm3 = fminf(cm3, fmaf(yxj[3], xv.x, fmaf(yyj[3], xv.y, fmaf(yzj[3], xv.z, xv.w))));
  }

  rmp[wave][lane+  0] = rm0;  cmp[wave][lane+  0] = cm0;
  rmp[wave][lane+ 64] = rm1;  cmp[wave][lane+ 64] = cm1;
  rmp[wave][lane+128] = rm2;  cmp[wave][lane+128] = cm2;
  rmp[wave][lane+192] = rm3;  cmp[wave][lane+192] = cm3;
  __syncthreads();

  float fx = xsd[tid].w + fminf(fminf(rmp[0][tid], rmp[1][tid]),
                                fminf(rmp[2][tid], rmp[3][tid]));
  float fy = ysd[tid].w + fminf(fminf(cmp[0][tid], cmp[1][tid]),
                                fminf(cmp[2][tid], cmp[3][tid]));
  float acc = fx + fy;

  for (int m = 32; m > 0; m >>= 1) acc += __shfl_xor(acc, m, 64);
  if (lane == 0) wpart[wave] = acc;
  __syncthreads();
  if (tid == 0) fitW[c] = (((wpart[0]+wpart[1])+wpart[2])+wpart[3]) * (1.0f/256.0f);
}

// ---------------- chamfer fitness for the final mean ----------------
__global__ __launch_bounds__(128) void k_eval(const float* __restrict__ pos, int Pn,
    const float* __restrict__ src_sub, const float* __restrict__ tgt_sub,
    float* __restrict__ fit){
  int c = blockIdx.x;
  int b = c / Pn;
  int tid = threadIdx.x;
  int wave = tid >> 6;
  int lane = tid & 63;
  __shared__ float4 ysd[SS];
  __shared__ float4 xsd[SS];
  __shared__ float wpart[2];

  const float* q = pos + (size_t)c*6;
  float R[9];
  axisangle_R(q[0], q[1], q[2], R);
  float tx=q[3], ty=q[4], tz=q[5];

  for (int i = tid; i < SS; i += 128){
    const float* tp = tgt_sub + ((size_t)b*SS + i)*3;
    float Y0=tp[0], Y1=tp[1], Y2=tp[2];
    float sy = fmaf(Y2,Y2, fmaf(Y1,Y1, Y0*Y0));
    ysd[i] = make_float4(-2.0f*Y0, -2.0f*Y1, -2.0f*Y2, sy);
  }

  int xi0 = wave*128 + lane;
  int xi1 = xi0 + 64;
  float px0,py0,pz0,sx0, px1,py1,pz1,sx1;
  {
    const float* sp = src_sub + ((size_t)b*SS + xi0)*3;
    float X0=sp[0], X1=sp[1], X2=sp[2];
    px0 = fmaf(X2, R[2], fmaf(X1, R[1], X0*R[0])) + tx;
    py0 = fmaf(X2, R[5], fmaf(X1, R[4], X0*R[3])) + ty;
    pz0 = fmaf(X2, R[8], fmaf(X1, R[7], X0*R[6])) + tz;
    sx0 = fmaf(pz0,pz0, fmaf(py0,py0, px0*px0));
    xsd[xi0] = make_float4(-2.0f*px0, -2.0f*py0, -2.0f*pz0, sx0);
  }
  {
    const float* sp = src_sub + ((size_t)b*SS + xi1)*3;
    float X0=sp[0], X1=sp[1], X2=sp[2];
    px1 = fmaf(X2, R[2], fmaf(X1, R[1], X0*R[0])) + tx;
    py1 = fmaf(X2, R[5], fmaf(X1, R[4], X0*R[3])) + ty;
    pz1 = fmaf(X2, R[8], fmaf(X1, R[7], X0*R[6])) + tz;
    sx1 = fmaf(pz1,pz1, fmaf(py1,py1, px1*px1));
    xsd[xi1] = make_float4(-2.0f*px1, -2.0f*py1, -2.0f*pz1, sx1);
  }
  __syncthreads();

  float rm0 = INFINITY, rm1 = INFINITY;
  #pragma unroll 8
  for (int t = 0; t < SS; ++t){
    float4 yv = ysd[t];
    rm0 = fminf(rm0, fmaf(px0, yv.x, fmaf(py0, yv.y, fmaf(pz0, yv.z, yv.w))));
    rm1 = fminf(rm1, fmaf(px1, yv.x, fmaf(py1, yv.y, fmaf(pz1, yv.z, yv.w))));
  }
  float acc = (sx0 + rm0) + (sx1 + rm1);

  float4 yv0 = ysd[xi0];
  float4 yv1 = ysd[xi1];
  float yx0 = -0.5f*yv0.x, yy0 = -0.5f*yv0.y, yz0 = -0.5f*yv0.z, sy0 = yv0.w;
  float yx1 = -0.5f*yv1.x, yy1 = -0.5f*yv1.y, yz1 = -0.5f*yv1.z, sy1 = yv1.w;
  float cm0 = INFINITY, cm1 = INFINITY;
  #pragma unroll 8
  for (int t = 0; t < SS; ++t){
    float4 xv = xsd[t];
    cm0 = fminf(cm0, fmaf(yx0, xv.x, fmaf(yy0, xv.y, fmaf(yz0, xv.z, xv.w))));
    cm1 = fminf(cm1, fmaf(yx1, xv.x, fmaf(yy1, xv.y, fmaf(yz1, xv.z, xv.w))));
  }
  acc += (sy0 + cm0) + (sy1 + cm1);

  for (int m = 32; m > 0; m >>= 1) acc += __shfl_xor(acc, m, 64);
  if (lane == 0) wpart[wave] = acc;
  __syncthreads();
  if (tid == 0) fit[c] = (wpart[0] + wpart[1]) * (1.0f/256.0f);
}

// ---------------- selection + update (final iteration only) ----------------
__global__ __launch_bounds__(64) void k_update(const float* __restrict__ fit,
    const float* __restrict__ off, const float* __restrict__ z,
    float* mean, float* sigma, float* gbest_pos, float* gbest_fit, WArr W){
  int b = blockIdx.x;
  int tid = threadIdx.x;
  __shared__ float lfit[POPP];
  __shared__ int order[POPP];
  __shared__ float mn[6], mz[6];
  if (tid < POPP) lfit[tid] = fit[b*POPP + tid];
  __syncthreads();
  if (tid < POPP){
    float f = lfit[tid];
    int r = 0;
    for (int j = 0; j < POPP; ++j){
      float fj = lfit[j];
      r += (fj < f) || (fj == f && j < tid);   // stable ascending rank
    }
    order[r] = tid;
  }
  __syncthreads();
  if (tid < 6){
    float a = 0.0f, bz = 0.0f;
    for (int m = 0; m < MUU; ++m){
      int idx = order[m];
      a  = fmaf(W.w[m], off[((size_t)b*POPP + idx)*6 + tid], a);
      bz = fmaf(W.w[m], z  [((size_t)b*POPP + idx)*6 + tid], bz);
    }
    mn[tid] = a; mz[tid] = bz;
  }
  __syncthreads();
  if (tid == 0){
    float avg = (((((fabsf(mz[0])+fabsf(mz[1]))+fabsf(mz[2]))+fabsf(mz[3]))+fabsf(mz[4]))+fabsf(mz[5])) / 6.0f;
    float e = expf(0.3f * (avg - 1.0f));
    for (int d = 0; d < 6; ++d){
      float sN = sigma[b*6 + d] * e;
      float lo = (d < 3) ? SLOR : SLOT;
      float hi = (d < 3) ? SHIR : SHIT;
      sN = fminf(fmaxf(sN, lo), hi);
      sigma[b*6 + d] = sN;
      mean[b*6 + d] = mn[d];
    }
    int i0 = order[0];
    float bf = lfit[i0];
    if (bf < gbest_fit[b]){
      gbest_fit[b] = bf;
      for (int d = 0; d < 6; ++d) gbest_pos[b*6 + d] = off[((size_t)b*POPP + i0)*6 + d];
    }
  }
}

// ---------------- finalize: choose gbest vs mean, emit R,t ----------------
__global__ void k_finalize(const float* mean, const float* mean_fit,
                           const float* gbest_pos, const float* gbest_fit, float* out){
  int b = blockIdx.x;
  if (threadIdx.x != 0) return;
  bool um = mean_fit[b] < gbest_fit[b];
  float g[6];
  for (int d = 0; d < 6; ++d) g[d] = um ? mean[b*6 + d] : gbest_pos[b*6 + d];
  float R[9];
  axisangle_R(g[0], g[1], g[2], R);
  for (int i = 0; i < 9; ++i) out[b*9 + i] = R[i];
  for (int d = 0; d < 3; ++d) out[NB*9 + b*3 + d] = g[3 + d];
}

__global__ void k_aligned(const float* __restrict__ src, const float* __restrict__ out_rt,
                          float* __restrict__ aligned){
  int idx = blockIdx.x*blockDim.x + threadIdx.x;
  if (idx >= NB*NPTS) return;
  int b = idx / NPTS;
  const float* R = out_rt + b*9;
  const float* t = out_rt + NB*9 + b*3;
  const float* p = src + (size_t)idx*3;
  float X0=p[0], X1=p[1], X2=p[2];
  float* o = aligned + (size_t)idx*3;
  o[0] = fmaf(X2, R[2], fmaf(X1, R[1], X0*R[0])) + t[0];
  o[1] = fmaf(X2, R[5], fmaf(X1, R[4], X0*R[3])) + t[1];
  o[2] = fmaf(X2, R[8], fmaf(X1, R[7], X0*R[6])) + t[2];
}

// ---------------- host ----------------
struct HKey { uint32_t a, b; };
static inline HKey h_tf(HKey k, uint32_t x0, uint32_t x1){
  uint32_t o0,o1; tf2x32(k.a, k.b, x0, x1, o0, o1);
  return {o0, o1};
}

extern "C" void kernel_launch(void* const* d_in, const int* in_sizes, int n_in,
                              void* d_out, int out_size, void* d_ws, size_t ws_size,
                              hipStream_t stream){
  const float* source = (const float*)d_in[0];
  const float* target = (const float*)d_in[1];
  float* out = (float*)d_out;

  // ---- workspace layout (256B aligned chunks; parity-doubled state buffers) ----
  uint8_t* w = (uint8_t*)d_ws;
  size_t o = 0;
  auto alloc = [&](size_t bytes){ void* p = w + o; o += (bytes + 255) & ~(size_t)255; return p; };
  uint64_t* comp    = (uint64_t*)alloc(2*(size_t)NPTS*8);
  uint64_t* grouped = (uint64_t*)alloc(2*(size_t)NPTS*8);
  int* perm1 = (int*)alloc(2*(size_t)NPTS*4);
  int* outS  = (int*)alloc(2*(size_t)SS*4);
  int* hs    = (int*)alloc(6*512*4);   // hist1|slot1|hist2|slot2|offs1|offs2 (512 ints each)
  float* src_sub   = (float*)alloc((size_t)NB*SS*3*4);
  float* tgt_sub   = (float*)alloc((size_t)NB*SS*3*4);
  float* z_buf     = (float*)alloc(2*(size_t)NB*POPP*6*4);
  float* off_buf   = (float*)alloc(2*(size_t)NB*POPP*6*4);
  float* fit_buf   = (float*)alloc(2*(size_t)NB*POPP*4);
  float* mean_buf  = (float*)alloc(2*(size_t)NB*6*4);
  float* sigma_buf = (float*)alloc(2*(size_t)NB*6*4);
  float* gb_pos    = (float*)alloc((size_t)NB*6*4);
  float* gb_fit    = (float*)alloc((size_t)NB*4);
  float* mean_fit  = (float*)alloc((size_t)NB*4);
  (void)ws_size; (void)in_sizes; (void)n_in; (void)out_size;

  int* hist1 = hs + 0*512;
  int* slot1 = hs + 1*512;
  int* hist2 = hs + 2*512;
  int* slot2 = hs + 3*512;
  int* offs1 = hs + 4*512;
  int* offs2 = hs + 5*512;

  // ---- host-side JAX key derivation (threefry, partitionable mode) ----
  HKey key0 = {0u, 42u};
  HKey k1 = h_tf(key0, 0u, 0u);
  HKey k2 = h_tf(key0, 0u, 1u);
  HKey k3 = h_tf(key0, 0u, 2u);
  HKey srcA  = h_tf(k1, 0u, 0u);
  HKey srcS1 = h_tf(k1, 0u, 1u);
  HKey srcS2 = h_tf(srcA, 0u, 1u);
  HKey tgtA  = h_tf(k2, 0u, 0u);
  HKey tgtS1 = h_tf(k2, 0u, 1u);
  HKey tgtS2 = h_tf(tgtA, 0u, 1u);
  HKey itk[NITERS];
  for (int j = 0; j < NITERS; ++j) itk[j] = h_tf(k3, 0u, (uint32_t)j);

  // ---- recombination weights (numpy double math, cast f32) ----
  WArr W;
  {
    double lw[MUU], s = 0.0;
    for (int m = 0; m < MUU; ++m){ lw[m] = log((double)MUU + 0.5) - log((double)(m+1)); s += lw[m]; }
    for (int m = 0; m < MUU; ++m) W.w[m] = (float)(lw[m] / s);
  }

  // zero hist/slot for both rounds (re-done every call -> deterministic)
  hipMemsetAsync(hs, 0, 4*512*4, stream);
  hipLaunchKernelGGL(k_init, dim3(1), dim3(256), 0, stream, mean_buf, sigma_buf, gb_pos, gb_fit);

  // ---- permutation round 1: rank by (key1, pos), payload = pos -> perm1 (full) ----
  hipLaunchKernelGGL(k_genc,  dim3(128), dim3(256), 0, stream,
                     comp, (const int*)nullptr, srcS1.a, srcS1.b, tgtS1.a, tgtS1.b, 0);
  hipLaunchKernelGGL(k_hist,  dim3(128), dim3(256), 0, stream, comp, hist1);
  hipLaunchKernelGGL(k_scan,  dim3(1),   dim3(64),  0, stream, hist1, offs1);
  hipLaunchKernelGGL(k_bscat, dim3(128), dim3(256), 0, stream, comp, offs1, slot1, grouped);
  hipLaunchKernelGGL(k_rank,  dim3(128), dim3(256), 0, stream, grouped, offs1, hist1, perm1, NPTS, NPTS);

  // ---- permutation round 2: rank by (key2, pos), payload = perm1 -> outS (first SS) ----
  hipLaunchKernelGGL(k_genc,  dim3(128), dim3(256), 0, stream,
                     comp, perm1, srcS2.a, srcS2.b, tgtS2.a, tgtS2.b, 1);
  hipLaunchKernelGGL(k_hist,  dim3(128), dim3(256), 0, stream, comp, hist2);
  hipLaunchKernelGGL(k_scan,  dim3(1),   dim3(64),  0, stream, hist2, offs2);
  hipLaunchKernelGGL(k_bscat, dim3(128), dim3(256), 0, stream, comp, offs2, slot2, grouped);
  hipLaunchKernelGGL(k_rank,  dim3(128), dim3(256), 0, stream, grouped, offs2, hist2, outS, SS, SS);

  hipLaunchKernelGGL(k_gather, dim3(64), dim3(256), 0, stream,
                     outS, source, target, src_sub, tgt_sub);

  // ---- CMA-ES main loop: ONE kernel per iteration (update fused as prologue) ----
  for (int it = 0; it < NITERS; ++it){
    hipLaunchKernelGGL(k_se, dim3(NB*POPP), dim3(256), 0, stream,
                       itk[it].a, itk[it].b, it, mean_buf, sigma_buf,
                       src_sub, tgt_sub, z_buf, off_buf, fit_buf,
                       gb_pos, gb_fit, W);
  }

  // ---- final (iteration-30) update on parity-1 state ----
  hipLaunchKernelGGL(k_update, dim3(NB), dim3(64), 0, stream,
                     fit_buf + NB*POPP, off_buf + (size_t)NB*POPP*6, z_buf + (size_t)NB*POPP*6,
                     mean_buf + NB*6, sigma_buf + NB*6, gb_pos, gb_fit, W);

  // ---- final mean evaluation + output ----
  hipLaunchKernelGGL(k_eval, dim3(NB), dim3(128), 0, stream,
                     mean_buf + NB*6, 1, src_sub, tgt_sub, mean_fit);
  hipLaunchKernelGGL(k_finalize, dim3(NB), dim3(64), 0, stream,
                     mean_buf + NB*6, mean_fit, gb_pos, gb_fit, out);
  hipLaunchKernelGGL(k_aligned, dim3((NB*NPTS + 255)/256), dim3(256), 0, stream,
                     source, out, out + NB*9 + NB*3);
}